// Round 4
// baseline (1426.888 us; speedup 1.0000x reference)
//
#include <hip/hip_runtime.h>
#include <stdint.h>

typedef unsigned int u32;
typedef unsigned short u16;

#define BUF_ELEMS (16384 * 256)

__device__ __forceinline__ float bflo(u32 u) { return __uint_as_float(u << 16); }
__device__ __forceinline__ float bfhi(u32 u) { return __uint_as_float(u & 0xffff0000u); }
__device__ __forceinline__ u16 f2bf(float f) {
    u32 u = __float_as_uint(f);
    return (u16)((u + 0x7fffu + ((u >> 16) & 1u)) >> 16);
}

#define GBK 32
#define LDT 68

// ---------------------------------------------------------------------------
// GEMM: C[16384,256](bf16 ws) = A(fp32) @ W[256,256](fp32) + bias(fp32).
// 64x64 tile, 256 threads, 4x4 per thread, fp32 LDS.
// ---------------------------------------------------------------------------
__global__ __launch_bounds__(256)
void gemm_f32a(const float* __restrict__ A, const float* __restrict__ W,
               const float* __restrict__ bias, u16* __restrict__ C)
{
    __shared__ __align__(16) float As[GBK][LDT];  // As[k][m]
    __shared__ __align__(16) float Bs[GBK][LDT];  // Bs[k][n]
    const int tid = threadIdx.x;
    const int m0 = (blockIdx.x >> 2) * 64;
    const int n0 = (blockIdx.x & 3) * 64;
    const int ty = tid >> 4, tx = tid & 15;
    const int ar = tid >> 2, ac = (tid & 3) * 8;
    const int br = tid >> 3, bc = (tid & 7) * 8;
    float acc[4][4] = {};

    for (int kt = 0; kt < 256; kt += GBK) {
        float4 a0 = *(const float4*)(A + (m0 + ar) * 256 + kt + ac);
        float4 a1 = *(const float4*)(A + (m0 + ar) * 256 + kt + ac + 4);
        float4 w0 = *(const float4*)(W + (kt + br) * 256 + n0 + bc);
        float4 w1 = *(const float4*)(W + (kt + br) * 256 + n0 + bc + 4);
        As[ac + 0][ar] = a0.x; As[ac + 1][ar] = a0.y;
        As[ac + 2][ar] = a0.z; As[ac + 3][ar] = a0.w;
        As[ac + 4][ar] = a1.x; As[ac + 5][ar] = a1.y;
        As[ac + 6][ar] = a1.z; As[ac + 7][ar] = a1.w;
        *(float4*)&Bs[br][bc]     = w0;
        *(float4*)&Bs[br][bc + 4] = w1;
        __syncthreads();
        #pragma unroll
        for (int kk = 0; kk < GBK; kk++) {
            float4 a4 = *(const float4*)&As[kk][ty * 4];
            float4 b4 = *(const float4*)&Bs[kk][tx * 4];
            float aa[4] = {a4.x, a4.y, a4.z, a4.w};
            float bb[4] = {b4.x, b4.y, b4.z, b4.w};
            #pragma unroll
            for (int i = 0; i < 4; i++)
                #pragma unroll
                for (int j = 0; j < 4; j++) acc[i][j] += aa[i] * bb[j];
        }
        __syncthreads();
    }
    const int cn = n0 + tx * 4;
    float4 bs4 = *(const float4*)(bias + cn);
    #pragma unroll
    for (int i = 0; i < 4; i++) {
        uint2 pk;
        pk.x = (u32)f2bf(acc[i][0] + bs4.x) | ((u32)f2bf(acc[i][1] + bs4.y) << 16);
        pk.y = (u32)f2bf(acc[i][2] + bs4.z) | ((u32)f2bf(acc[i][3] + bs4.w) << 16);
        *(uint2*)(C + (m0 + ty * 4 + i) * 256 + cn) = pk;
    }
}

// ---------------------------------------------------------------------------
// GEMM: C[16384,256](bf16 ws) = A(bf16 ws) @ W[256,256](fp32) + bias(fp32).
// ---------------------------------------------------------------------------
__global__ __launch_bounds__(256)
void gemm_bf16a(const u16* __restrict__ A, const float* __restrict__ W,
                const float* __restrict__ bias, u16* __restrict__ C)
{
    __shared__ __align__(16) float As[GBK][LDT];
    __shared__ __align__(16) float Bs[GBK][LDT];
    const int tid = threadIdx.x;
    const int m0 = (blockIdx.x >> 2) * 64;
    const int n0 = (blockIdx.x & 3) * 64;
    const int ty = tid >> 4, tx = tid & 15;
    const int ar = tid >> 2, ac = (tid & 3) * 8;
    const int br = tid >> 3, bc = (tid & 7) * 8;
    float acc[4][4] = {};

    for (int kt = 0; kt < 256; kt += GBK) {
        uint4 av = *(const uint4*)(A + (m0 + ar) * 256 + kt + ac);
        float4 w0 = *(const float4*)(W + (kt + br) * 256 + n0 + bc);
        float4 w1 = *(const float4*)(W + (kt + br) * 256 + n0 + bc + 4);
        As[ac + 0][ar] = bflo(av.x); As[ac + 1][ar] = bfhi(av.x);
        As[ac + 2][ar] = bflo(av.y); As[ac + 3][ar] = bfhi(av.y);
        As[ac + 4][ar] = bflo(av.z); As[ac + 5][ar] = bfhi(av.z);
        As[ac + 6][ar] = bflo(av.w); As[ac + 7][ar] = bfhi(av.w);
        *(float4*)&Bs[br][bc]     = w0;
        *(float4*)&Bs[br][bc + 4] = w1;
        __syncthreads();
        #pragma unroll
        for (int kk = 0; kk < GBK; kk++) {
            float4 a4 = *(const float4*)&As[kk][ty * 4];
            float4 b4 = *(const float4*)&Bs[kk][tx * 4];
            float aa[4] = {a4.x, a4.y, a4.z, a4.w};
            float bb[4] = {b4.x, b4.y, b4.z, b4.w};
            #pragma unroll
            for (int i = 0; i < 4; i++)
                #pragma unroll
                for (int j = 0; j < 4; j++) acc[i][j] += aa[i] * bb[j];
        }
        __syncthreads();
    }
    const int cn = n0 + tx * 4;
    float4 bs4 = *(const float4*)(bias + cn);
    #pragma unroll
    for (int i = 0; i < 4; i++) {
        uint2 pk;
        pk.x = (u32)f2bf(acc[i][0] + bs4.x) | ((u32)f2bf(acc[i][1] + bs4.y) << 16);
        pk.y = (u32)f2bf(acc[i][2] + bs4.z) | ((u32)f2bf(acc[i][3] + bs4.w) << 16);
        *(uint2*)(C + (m0 + ty * 4 + i) * 256 + cn) = pk;
    }
}

// ---------------------------------------------------------------------------
// Enhancement GEMM -> d_out (FP32): C = A1(bf16)@W[0:256,:] +
// A2(bf16)@W[256:512,:] + bias; W[512,256], bias fp32.
// ---------------------------------------------------------------------------
__global__ __launch_bounds__(256)
void gemm_enh(const u16* __restrict__ A1, const u16* __restrict__ A2,
              const float* __restrict__ W, const float* __restrict__ bias,
              float* __restrict__ C)
{
    __shared__ __align__(16) float As[GBK][LDT];
    __shared__ __align__(16) float Bs[GBK][LDT];
    const int tid = threadIdx.x;
    const int m0 = (blockIdx.x >> 2) * 64;
    const int n0 = (blockIdx.x & 3) * 64;
    const int ty = tid >> 4, tx = tid & 15;
    const int ar = tid >> 2, ac = (tid & 3) * 8;
    const int br = tid >> 3, bc = (tid & 7) * 8;
    float acc[4][4] = {};

    for (int kt = 0; kt < 512; kt += GBK) {
        const u16* Asrc = (kt < 256) ? A1 : A2;
        uint4 av = *(const uint4*)(Asrc + (m0 + ar) * 256 + (kt & 255) + ac);
        float4 w0 = *(const float4*)(W + (kt + br) * 256 + n0 + bc);
        float4 w1 = *(const float4*)(W + (kt + br) * 256 + n0 + bc + 4);
        As[ac + 0][ar] = bflo(av.x); As[ac + 1][ar] = bfhi(av.x);
        As[ac + 2][ar] = bflo(av.y); As[ac + 3][ar] = bfhi(av.y);
        As[ac + 4][ar] = bflo(av.z); As[ac + 5][ar] = bfhi(av.z);
        As[ac + 6][ar] = bflo(av.w); As[ac + 7][ar] = bfhi(av.w);
        *(float4*)&Bs[br][bc]     = w0;
        *(float4*)&Bs[br][bc + 4] = w1;
        __syncthreads();
        #pragma unroll
        for (int kk = 0; kk < GBK; kk++) {
            float4 a4 = *(const float4*)&As[kk][ty * 4];
            float4 b4 = *(const float4*)&Bs[kk][tx * 4];
            float aa[4] = {a4.x, a4.y, a4.z, a4.w};
            float bb[4] = {b4.x, b4.y, b4.z, b4.w};
            #pragma unroll
            for (int i = 0; i < 4; i++)
                #pragma unroll
                for (int j = 0; j < 4; j++) acc[i][j] += aa[i] * bb[j];
        }
        __syncthreads();
    }
    const int cn = n0 + tx * 4;
    float4 bs4 = *(const float4*)(bias + cn);
    #pragma unroll
    for (int i = 0; i < 4; i++) {
        float4 ov;
        ov.x = acc[i][0] + bs4.x;
        ov.y = acc[i][1] + bs4.y;
        ov.z = acc[i][2] + bs4.z;
        ov.w = acc[i][3] + bs4.w;
        *(float4*)(C + (m0 + ty * 4 + i) * 256 + cn) = ov;
    }
}

// ---------------------------------------------------------------------------
// Attention (one set, bf16 ws). One thread = one query row; no-max softmax
// (scores O(1) by construction; fp32 exp cannot overflow for |s| < ~80).
// grid 512 = 16(b) * 8(h) * 4(q-quarter); block 256.
// ---------------------------------------------------------------------------
__global__ __launch_bounds__(256)
void attn_kernel(const u16* __restrict__ Q, const u16* __restrict__ K,
                 const u16* __restrict__ V, u16* __restrict__ O)
{
    __shared__ uint4 Ks4[512];
    __shared__ uint4 Vs4[512];
    const int tid = threadIdx.x;
    const int bid = blockIdx.x;
    const int qt = bid & 3;
    const int h = (bid >> 2) & 7;
    const int b = bid >> 5;
    const int rowbase = b * 1024;
    const int q = qt * 256 + tid;
    const float scale = 0.17677669529663687f;

    float qa[32];
    {
        const uint4* qp = (const uint4*)(Q + (rowbase + q) * 256 + h * 32);
        #pragma unroll
        for (int c = 0; c < 4; c++) {
            uint4 v = qp[c];
            qa[c*8+0] = bflo(v.x)*scale; qa[c*8+1] = bfhi(v.x)*scale;
            qa[c*8+2] = bflo(v.y)*scale; qa[c*8+3] = bfhi(v.y)*scale;
            qa[c*8+4] = bflo(v.z)*scale; qa[c*8+5] = bfhi(v.z)*scale;
            qa[c*8+6] = bflo(v.w)*scale; qa[c*8+7] = bfhi(v.w)*scale;
        }
    }

    float l = 0.f;
    float acc[32];
    #pragma unroll
    for (int j = 0; j < 32; j++) acc[j] = 0.f;

    for (int t = 0; t < 8; t++) {
        #pragma unroll
        for (int i = 0; i < 2; i++) {
            int u = tid + i * 256;
            int row = u >> 2, c = u & 3;
            int g = (rowbase + t * 128 + row) * 256 + h * 32 + c * 8;
            Ks4[u] = *(const uint4*)(K + g);
            Vs4[u] = *(const uint4*)(V + g);
        }
        __syncthreads();
        for (int k = 0; k < 128; k++) {
            float s = 0.f;
            #pragma unroll
            for (int c = 0; c < 4; c++) {
                uint4 kv = Ks4[k * 4 + c];
                int j = c * 8;
                s += qa[j]  *bflo(kv.x) + qa[j+1]*bfhi(kv.x)
                   + qa[j+2]*bflo(kv.y) + qa[j+3]*bfhi(kv.y)
                   + qa[j+4]*bflo(kv.z) + qa[j+5]*bfhi(kv.z)
                   + qa[j+6]*bflo(kv.w) + qa[j+7]*bfhi(kv.w);
            }
            float p = __expf(s);
            l += p;
            #pragma unroll
            for (int c = 0; c < 4; c++) {
                uint4 vv = Vs4[k * 4 + c];
                int j = c * 8;
                acc[j]   += p * bflo(vv.x); acc[j+1] += p * bfhi(vv.x);
                acc[j+2] += p * bflo(vv.y); acc[j+3] += p * bfhi(vv.y);
                acc[j+4] += p * bflo(vv.z); acc[j+5] += p * bfhi(vv.z);
                acc[j+6] += p * bflo(vv.w); acc[j+7] += p * bfhi(vv.w);
            }
        }
        __syncthreads();
    }

    float inv = 1.f / l;
    u16* o = O + (rowbase + q) * 256 + h * 32;
    #pragma unroll
    for (int c = 0; c < 4; c++) {
        uint4 ov;
        ov.x = (u32)f2bf(acc[c*8+0]*inv) | ((u32)f2bf(acc[c*8+1]*inv) << 16);
        ov.y = (u32)f2bf(acc[c*8+2]*inv) | ((u32)f2bf(acc[c*8+3]*inv) << 16);
        ov.z = (u32)f2bf(acc[c*8+4]*inv) | ((u32)f2bf(acc[c*8+5]*inv) << 16);
        ov.w = (u32)f2bf(acc[c*8+6]*inv) | ((u32)f2bf(acc[c*8+7]*inv) << 16);
        *(uint4*)(o + c * 8) = ov;
    }
}

// ---------------------------------------------------------------------------
// Residual + LayerNorm: out(bf16 ws) = LN(P(bf16) + R(fp32)) * g + beta.
// ---------------------------------------------------------------------------
__global__ __launch_bounds__(256)
void ln_res_kernel(const u16* __restrict__ P, const float* __restrict__ R,
                   const float* __restrict__ g, const float* __restrict__ beta,
                   u16* __restrict__ out)
{
    const int lane = threadIdx.x & 63;
    const int row = blockIdx.x * 4 + (threadIdx.x >> 6);
    const int col = lane * 4;
    uint2 pv = *(const uint2*)(P + row * 256 + col);
    float4 rv = *(const float4*)(R + row * 256 + col);
    float x0 = bflo(pv.x) + rv.x;
    float x1 = bfhi(pv.x) + rv.y;
    float x2 = bflo(pv.y) + rv.z;
    float x3 = bfhi(pv.y) + rv.w;
    float s = x0 + x1 + x2 + x3;
    float s2 = x0*x0 + x1*x1 + x2*x2 + x3*x3;
    #pragma unroll
    for (int off = 32; off > 0; off >>= 1) {
        s  += __shfl_xor(s, off);
        s2 += __shfl_xor(s2, off);
    }
    float mean = s * 0.00390625f;
    float var = fmaxf(s2 * 0.00390625f - mean * mean, 0.f);
    float rstd = rsqrtf(var + 1e-5f);
    float4 gv = *(const float4*)(g + col);
    float4 bv = *(const float4*)(beta + col);
    uint2 pk;
    pk.x = (u32)f2bf((x0 - mean) * rstd * gv.x + bv.x)
         | ((u32)f2bf((x1 - mean) * rstd * gv.y + bv.y) << 16);
    pk.y = (u32)f2bf((x2 - mean) * rstd * gv.z + bv.z)
         | ((u32)f2bf((x3 - mean) * rstd * gv.w + bv.w) << 16);
    *(uint2*)(out + row * 256 + col) = pk;
}

// ---------------------------------------------------------------------------
// Inconsistency + passthroughs -> d_out (FP32).
// ---------------------------------------------------------------------------
__global__ __launch_bounds__(256)
void inc_kernel(const float* __restrict__ img_sp, const float* __restrict__ txt_sp,
                const float* __restrict__ W, const float* __restrict__ bias,
                float* __restrict__ out_inc, float* __restrict__ out_img,
                float* __restrict__ out_txt)
{
    __shared__ float iv[512];
    const int b = blockIdx.x, n = threadIdx.x;
    float a = img_sp[b * 256 + n];
    float t = txt_sp[b * 256 + n];
    iv[n] = a - t;
    iv[256 + n] = a * t;
    __syncthreads();
    float acc = bias[n];
    for (int k = 0; k < 512; k++) acc += iv[k] * W[k * 256 + n];
    out_inc[b * 256 + n] = acc;
    out_img[b * 256 + n] = a;
    out_txt[b * 256 + n] = t;
}

// ---------------------------------------------------------------------------
extern "C" void kernel_launch(void* const* d_in, const int* in_sizes, int n_in,
                              void* d_out, int out_size, void* d_ws, size_t ws_size,
                              hipStream_t stream)
{
    (void)in_sizes; (void)n_in; (void)out_size; (void)ws_size;
    const float* img    = (const float*)d_in[0];
    const float* txt    = (const float*)d_in[1];
    const float* img_sp = (const float*)d_in[2];
    const float* txt_sp = (const float*)d_in[3];
    const float* wq_i = (const float*)d_in[4];  const float* bq_i = (const float*)d_in[5];
    const float* wk_i = (const float*)d_in[6];  const float* bk_i = (const float*)d_in[7];
    const float* wv_i = (const float*)d_in[8];  const float* bv_i = (const float*)d_in[9];
    const float* wo_i = (const float*)d_in[10]; const float* bo_i = (const float*)d_in[11];
    const float* wq_t = (const float*)d_in[12]; const float* bq_t = (const float*)d_in[13];
    const float* wk_t = (const float*)d_in[14]; const float* bk_t = (const float*)d_in[15];
    const float* wv_t = (const float*)d_in[16]; const float* bv_t = (const float*)d_in[17];
    const float* wo_t = (const float*)d_in[18]; const float* bo_t = (const float*)d_in[19];
    const float* lng_i = (const float*)d_in[20]; const float* lnb_i = (const float*)d_in[21];
    const float* lng_t = (const float*)d_in[22]; const float* lnb_t = (const float*)d_in[23];
    const float* enh_w = (const float*)d_in[24]; const float* enh_b = (const float*)d_in[25];
    const float* incw  = (const float*)d_in[26]; const float* incb  = (const float*)d_in[27];
    float* out = (float*)d_out;
    u16* wsp = (u16*)d_ws;
    u16* b0 = wsp;
    u16* b1 = wsp + 1 * (size_t)BUF_ELEMS;
    u16* b2 = wsp + 2 * (size_t)BUF_ELEMS;
    u16* b3 = wsp + 3 * (size_t)BUF_ELEMS;
    u16* b4 = wsp + 4 * (size_t)BUF_ELEMS;
    u16* b5 = wsp + 5 * (size_t)BUF_ELEMS;

    dim3 blk(256);
    // ---- i2t MHA: Q from img, K/V from txt ----
    gemm_f32a<<<1024, blk, 0, stream>>>(img, wq_i, bq_i, b0);
    gemm_f32a<<<1024, blk, 0, stream>>>(txt, wk_i, bk_i, b1);
    gemm_f32a<<<1024, blk, 0, stream>>>(txt, wv_i, bv_i, b2);
    attn_kernel<<<512, blk, 0, stream>>>(b0, b1, b2, b3);
    gemm_bf16a<<<1024, blk, 0, stream>>>(b3, wo_i, bo_i, b4);
    ln_res_kernel<<<4096, blk, 0, stream>>>(b4, img, lng_i, lnb_i, b5);  // b5 = img_query
    // ---- t2i MHA: Q from txt, K/V from img ----
    gemm_f32a<<<1024, blk, 0, stream>>>(txt, wq_t, bq_t, b0);
    gemm_f32a<<<1024, blk, 0, stream>>>(img, wk_t, bk_t, b1);
    gemm_f32a<<<1024, blk, 0, stream>>>(img, wv_t, bv_t, b2);
    attn_kernel<<<512, blk, 0, stream>>>(b0, b1, b2, b3);
    gemm_bf16a<<<1024, blk, 0, stream>>>(b3, wo_t, bo_t, b4);
    ln_res_kernel<<<4096, blk, 0, stream>>>(b4, txt, lng_t, lnb_t, b1);  // b1 = txt_query
    // ---- enhancement + inconsistency (both straight into fp32 d_out) ----
    gemm_enh<<<1024, blk, 0, stream>>>(b5, b1, enh_w, enh_b, out);
    inc_kernel<<<16, blk, 0, stream>>>(img_sp, txt_sp, incw, incb,
                                       out + 4194304, out + 4198400, out + 4202496);
}

// Round 5
// 620.467 us; speedup vs baseline: 2.2997x; 2.2997x over previous
//
#include <hip/hip_runtime.h>
#include <stdint.h>

typedef unsigned int u32;
typedef unsigned short u16;
typedef __attribute__((ext_vector_type(8))) short bf16x8;
typedef __attribute__((ext_vector_type(4))) float f32x4;

#define BUF_ELEMS (16384 * 256)

__device__ __forceinline__ float bflo(u32 u) { return __uint_as_float(u << 16); }
__device__ __forceinline__ float bfhi(u32 u) { return __uint_as_float(u & 0xffff0000u); }
__device__ __forceinline__ u16 f2bf(float f) {
    u32 u = __float_as_uint(f);
    return (u16)((u + 0x7fffu + ((u >> 16) & 1u)) >> 16);
}

#define GBK 32
#define LDT 68

// ---------------------------------------------------------------------------
// GEMM: C[16384,256](bf16 ws) = A(fp32) @ W[256,256](fp32) + bias(fp32).
// ---------------------------------------------------------------------------
__global__ __launch_bounds__(256)
void gemm_f32a(const float* __restrict__ A, const float* __restrict__ W,
               const float* __restrict__ bias, u16* __restrict__ C)
{
    __shared__ __align__(16) float As[GBK][LDT];  // As[k][m]
    __shared__ __align__(16) float Bs[GBK][LDT];  // Bs[k][n]
    const int tid = threadIdx.x;
    const int m0 = (blockIdx.x >> 2) * 64;
    const int n0 = (blockIdx.x & 3) * 64;
    const int ty = tid >> 4, tx = tid & 15;
    const int ar = tid >> 2, ac = (tid & 3) * 8;
    const int br = tid >> 3, bc = (tid & 7) * 8;
    float acc[4][4] = {};

    for (int kt = 0; kt < 256; kt += GBK) {
        float4 a0 = *(const float4*)(A + (m0 + ar) * 256 + kt + ac);
        float4 a1 = *(const float4*)(A + (m0 + ar) * 256 + kt + ac + 4);
        float4 w0 = *(const float4*)(W + (kt + br) * 256 + n0 + bc);
        float4 w1 = *(const float4*)(W + (kt + br) * 256 + n0 + bc + 4);
        As[ac + 0][ar] = a0.x; As[ac + 1][ar] = a0.y;
        As[ac + 2][ar] = a0.z; As[ac + 3][ar] = a0.w;
        As[ac + 4][ar] = a1.x; As[ac + 5][ar] = a1.y;
        As[ac + 6][ar] = a1.z; As[ac + 7][ar] = a1.w;
        *(float4*)&Bs[br][bc]     = w0;
        *(float4*)&Bs[br][bc + 4] = w1;
        __syncthreads();
        #pragma unroll
        for (int kk = 0; kk < GBK; kk++) {
            float4 a4 = *(const float4*)&As[kk][ty * 4];
            float4 b4 = *(const float4*)&Bs[kk][tx * 4];
            float aa[4] = {a4.x, a4.y, a4.z, a4.w};
            float bb[4] = {b4.x, b4.y, b4.z, b4.w};
            #pragma unroll
            for (int i = 0; i < 4; i++)
                #pragma unroll
                for (int j = 0; j < 4; j++) acc[i][j] += aa[i] * bb[j];
        }
        __syncthreads();
    }
    const int cn = n0 + tx * 4;
    float4 bs4 = *(const float4*)(bias + cn);
    #pragma unroll
    for (int i = 0; i < 4; i++) {
        uint2 pk;
        pk.x = (u32)f2bf(acc[i][0] + bs4.x) | ((u32)f2bf(acc[i][1] + bs4.y) << 16);
        pk.y = (u32)f2bf(acc[i][2] + bs4.z) | ((u32)f2bf(acc[i][3] + bs4.w) << 16);
        *(uint2*)(C + (m0 + ty * 4 + i) * 256 + cn) = pk;
    }
}

// ---------------------------------------------------------------------------
// GEMM: C[16384,256](bf16 ws) = A(bf16 ws) @ W[256,256](fp32) + bias(fp32).
// ---------------------------------------------------------------------------
__global__ __launch_bounds__(256)
void gemm_bf16a(const u16* __restrict__ A, const float* __restrict__ W,
                const float* __restrict__ bias, u16* __restrict__ C)
{
    __shared__ __align__(16) float As[GBK][LDT];
    __shared__ __align__(16) float Bs[GBK][LDT];
    const int tid = threadIdx.x;
    const int m0 = (blockIdx.x >> 2) * 64;
    const int n0 = (blockIdx.x & 3) * 64;
    const int ty = tid >> 4, tx = tid & 15;
    const int ar = tid >> 2, ac = (tid & 3) * 8;
    const int br = tid >> 3, bc = (tid & 7) * 8;
    float acc[4][4] = {};

    for (int kt = 0; kt < 256; kt += GBK) {
        uint4 av = *(const uint4*)(A + (m0 + ar) * 256 + kt + ac);
        float4 w0 = *(const float4*)(W + (kt + br) * 256 + n0 + bc);
        float4 w1 = *(const float4*)(W + (kt + br) * 256 + n0 + bc + 4);
        As[ac + 0][ar] = bflo(av.x); As[ac + 1][ar] = bfhi(av.x);
        As[ac + 2][ar] = bflo(av.y); As[ac + 3][ar] = bfhi(av.y);
        As[ac + 4][ar] = bflo(av.z); As[ac + 5][ar] = bfhi(av.z);
        As[ac + 6][ar] = bflo(av.w); As[ac + 7][ar] = bfhi(av.w);
        *(float4*)&Bs[br][bc]     = w0;
        *(float4*)&Bs[br][bc + 4] = w1;
        __syncthreads();
        #pragma unroll
        for (int kk = 0; kk < GBK; kk++) {
            float4 a4 = *(const float4*)&As[kk][ty * 4];
            float4 b4 = *(const float4*)&Bs[kk][tx * 4];
            float aa[4] = {a4.x, a4.y, a4.z, a4.w};
            float bb[4] = {b4.x, b4.y, b4.z, b4.w};
            #pragma unroll
            for (int i = 0; i < 4; i++)
                #pragma unroll
                for (int j = 0; j < 4; j++) acc[i][j] += aa[i] * bb[j];
        }
        __syncthreads();
    }
    const int cn = n0 + tx * 4;
    float4 bs4 = *(const float4*)(bias + cn);
    #pragma unroll
    for (int i = 0; i < 4; i++) {
        uint2 pk;
        pk.x = (u32)f2bf(acc[i][0] + bs4.x) | ((u32)f2bf(acc[i][1] + bs4.y) << 16);
        pk.y = (u32)f2bf(acc[i][2] + bs4.z) | ((u32)f2bf(acc[i][3] + bs4.w) << 16);
        *(uint2*)(C + (m0 + ty * 4 + i) * 256 + cn) = pk;
    }
}

// ---------------------------------------------------------------------------
// Enhancement GEMM -> d_out (FP32): C = A1(bf16)@W[0:256,:] +
// A2(bf16)@W[256:512,:] + bias.
// ---------------------------------------------------------------------------
__global__ __launch_bounds__(256)
void gemm_enh(const u16* __restrict__ A1, const u16* __restrict__ A2,
              const float* __restrict__ W, const float* __restrict__ bias,
              float* __restrict__ C)
{
    __shared__ __align__(16) float As[GBK][LDT];
    __shared__ __align__(16) float Bs[GBK][LDT];
    const int tid = threadIdx.x;
    const int m0 = (blockIdx.x >> 2) * 64;
    const int n0 = (blockIdx.x & 3) * 64;
    const int ty = tid >> 4, tx = tid & 15;
    const int ar = tid >> 2, ac = (tid & 3) * 8;
    const int br = tid >> 3, bc = (tid & 7) * 8;
    float acc[4][4] = {};

    for (int kt = 0; kt < 512; kt += GBK) {
        const u16* Asrc = (kt < 256) ? A1 : A2;
        uint4 av = *(const uint4*)(Asrc + (m0 + ar) * 256 + (kt & 255) + ac);
        float4 w0 = *(const float4*)(W + (kt + br) * 256 + n0 + bc);
        float4 w1 = *(const float4*)(W + (kt + br) * 256 + n0 + bc + 4);
        As[ac + 0][ar] = bflo(av.x); As[ac + 1][ar] = bfhi(av.x);
        As[ac + 2][ar] = bflo(av.y); As[ac + 3][ar] = bfhi(av.y);
        As[ac + 4][ar] = bflo(av.z); As[ac + 5][ar] = bfhi(av.z);
        As[ac + 6][ar] = bflo(av.w); As[ac + 7][ar] = bfhi(av.w);
        *(float4*)&Bs[br][bc]     = w0;
        *(float4*)&Bs[br][bc + 4] = w1;
        __syncthreads();
        #pragma unroll
        for (int kk = 0; kk < GBK; kk++) {
            float4 a4 = *(const float4*)&As[kk][ty * 4];
            float4 b4 = *(const float4*)&Bs[kk][tx * 4];
            float aa[4] = {a4.x, a4.y, a4.z, a4.w};
            float bb[4] = {b4.x, b4.y, b4.z, b4.w};
            #pragma unroll
            for (int i = 0; i < 4; i++)
                #pragma unroll
                for (int j = 0; j < 4; j++) acc[i][j] += aa[i] * bb[j];
        }
        __syncthreads();
    }
    const int cn = n0 + tx * 4;
    float4 bs4 = *(const float4*)(bias + cn);
    #pragma unroll
    for (int i = 0; i < 4; i++) {
        float4 ov;
        ov.x = acc[i][0] + bs4.x;
        ov.y = acc[i][1] + bs4.y;
        ov.z = acc[i][2] + bs4.z;
        ov.w = acc[i][3] + bs4.w;
        *(float4*)(C + (m0 + ty * 4 + i) * 256 + cn) = ov;
    }
}

// ---------------------------------------------------------------------------
// MFMA flash attention (no-max softmax, validated in round 4).
//   Block: 256 thr = 4 waves; Q-tile 64 rows (16/wave); K-tile 128 keys.
//   QK^T: mfma_f32_16x16x32_bf16, A=Q[m=q][k=dim], B=K[n=key][k=dim],
//         hd=32 = exactly one MFMA K-step. D[q=(quad*4+reg)][key=lane&15].
//   P: exp2(s*scale*log2e) -> bf16 -> LDS (C-layout -> A-layout transform).
//   PV: A=P[m=q][k=key], B=V^T[n=dim][k=key] (Vt staged transposed),
//       O accumulates in MFMA C across all 8 K-tiles (no rescale needed).
//   l: fp32 per-lane partials, one 16-lane shfl reduce at the end.
// grid 2048 = 16(b) * 8(h) * 16(q-tile); block 256.
// ---------------------------------------------------------------------------
__global__ __launch_bounds__(256)
void attn_mfma(const u16* __restrict__ Q, const u16* __restrict__ K,
               const u16* __restrict__ V, u16* __restrict__ O)
{
    __shared__ u16 Ks[128][40];      // K-tile, pad 32->40 (2-way-free reads)
    __shared__ u16 Vt[32][136];      // V-tile transposed [dim][key], pad 136
    __shared__ u16 Ps[4][16][136];   // per-wave P tile [q][key]
    const int tid = threadIdx.x;
    const int wave = tid >> 6, lane = tid & 63;
    const int L = lane & 15, Qd = lane >> 4;
    const int qt = blockIdx.x & 15;
    const int h = (blockIdx.x >> 4) & 7;
    const int b = blockIdx.x >> 7;
    const int rowbase = b * 1024;
    const float sc2 = 0.17677669529663687f * 1.4426950408889634f; // 1/sqrt(32)*log2(e)

    // Q fragment: A[m=L][k=Qd*8+j], one 16B load
    const int qrow = rowbase + qt * 64 + wave * 16 + L;
    bf16x8 qfrag = *(const bf16x8*)(Q + (size_t)qrow * 256 + h * 32 + Qd * 8);

    f32x4 oacc0 = {0.f, 0.f, 0.f, 0.f};
    f32x4 oacc1 = {0.f, 0.f, 0.f, 0.f};
    float lpart[4] = {0.f, 0.f, 0.f, 0.f};

    const int sr = tid >> 1;          // staging row 0..127
    const int scol = (tid & 1) * 16;  // staging col 0/16

    for (int t = 0; t < 8; t++) {
        // ---- stage K[128][32] and V^T[32][128] ----
        const size_t kvbase = (size_t)(rowbase + t * 128 + sr) * 256 + h * 32 + scol;
        uint4 k1 = *(const uint4*)(K + kvbase);
        uint4 k2 = *(const uint4*)(K + kvbase + 8);
        uint4 v1 = *(const uint4*)(V + kvbase);
        uint4 v2 = *(const uint4*)(V + kvbase + 8);
        *(uint4*)&Ks[sr][scol]     = k1;
        *(uint4*)&Ks[sr][scol + 8] = k2;
        union { uint4 u4[2]; u16 us[16]; } vv;
        vv.u4[0] = v1; vv.u4[1] = v2;
        #pragma unroll
        for (int j = 0; j < 16; j++) Vt[scol + j][sr] = vv.us[j];
        __syncthreads();

        // ---- S = Q K^T : 8 col-tiles of 16 keys ----
        const f32x4 z = {0.f, 0.f, 0.f, 0.f};
        f32x4 sacc[8];
        #pragma unroll
        for (int ct = 0; ct < 8; ct++) {
            bf16x8 kfrag = *(const bf16x8*)&Ks[ct * 16 + L][Qd * 8];
            sacc[ct] = __builtin_amdgcn_mfma_f32_16x16x32_bf16(qfrag, kfrag, z, 0, 0, 0);
        }
        // ---- p = exp2(s*sc2); accumulate l; P -> LDS bf16 ----
        #pragma unroll
        for (int ct = 0; ct < 8; ct++) {
            #pragma unroll
            for (int r = 0; r < 4; r++) {
                float p = exp2f(sacc[ct][r] * sc2);
                lpart[r] += p;
                Ps[wave][Qd * 4 + r][ct * 16 + L] = f2bf(p);
            }
        }
        // ---- O += P V : 4 key-chunks x 2 dim-tiles ----
        #pragma unroll
        for (int kc = 0; kc < 4; kc++) {
            bf16x8 pfrag = *(const bf16x8*)&Ps[wave][L][kc * 32 + Qd * 8];
            bf16x8 vf0 = *(const bf16x8*)&Vt[L][kc * 32 + Qd * 8];
            bf16x8 vf1 = *(const bf16x8*)&Vt[16 + L][kc * 32 + Qd * 8];
            oacc0 = __builtin_amdgcn_mfma_f32_16x16x32_bf16(pfrag, vf0, oacc0, 0, 0, 0);
            oacc1 = __builtin_amdgcn_mfma_f32_16x16x32_bf16(pfrag, vf1, oacc1, 0, 0, 0);
        }
        __syncthreads();
    }

    // ---- row sums: reduce across the 16 lanes of each quad-group ----
    #pragma unroll
    for (int r = 0; r < 4; r++) {
        float v = lpart[r];
        v += __shfl_xor(v, 1); v += __shfl_xor(v, 2);
        v += __shfl_xor(v, 4); v += __shfl_xor(v, 8);
        lpart[r] = 1.f / v;
    }
    // ---- write O (bf16 ws): row=(quad*4+reg), col=h*32 + nt*16 + L ----
    #pragma unroll
    for (int r = 0; r < 4; r++) {
        const size_t orow = (size_t)(rowbase + qt * 64 + wave * 16 + Qd * 4 + r) * 256 + h * 32;
        O[orow + L]      = f2bf(oacc0[r] * lpart[r]);
        O[orow + 16 + L] = f2bf(oacc1[r] * lpart[r]);
    }
}

// ---------------------------------------------------------------------------
// Residual + LayerNorm: out(bf16 ws) = LN(P(bf16) + R(fp32)) * g + beta.
// ---------------------------------------------------------------------------
__global__ __launch_bounds__(256)
void ln_res_kernel(const u16* __restrict__ P, const float* __restrict__ R,
                   const float* __restrict__ g, const float* __restrict__ beta,
                   u16* __restrict__ out)
{
    const int lane = threadIdx.x & 63;
    const int row = blockIdx.x * 4 + (threadIdx.x >> 6);
    const int col = lane * 4;
    uint2 pv = *(const uint2*)(P + row * 256 + col);
    float4 rv = *(const float4*)(R + row * 256 + col);
    float x0 = bflo(pv.x) + rv.x;
    float x1 = bfhi(pv.x) + rv.y;
    float x2 = bflo(pv.y) + rv.z;
    float x3 = bfhi(pv.y) + rv.w;
    float s = x0 + x1 + x2 + x3;
    float s2 = x0*x0 + x1*x1 + x2*x2 + x3*x3;
    #pragma unroll
    for (int off = 32; off > 0; off >>= 1) {
        s  += __shfl_xor(s, off);
        s2 += __shfl_xor(s2, off);
    }
    float mean = s * 0.00390625f;
    float var = fmaxf(s2 * 0.00390625f - mean * mean, 0.f);
    float rstd = rsqrtf(var + 1e-5f);
    float4 gv = *(const float4*)(g + col);
    float4 bv = *(const float4*)(beta + col);
    uint2 pk;
    pk.x = (u32)f2bf((x0 - mean) * rstd * gv.x + bv.x)
         | ((u32)f2bf((x1 - mean) * rstd * gv.y + bv.y) << 16);
    pk.y = (u32)f2bf((x2 - mean) * rstd * gv.z + bv.z)
         | ((u32)f2bf((x3 - mean) * rstd * gv.w + bv.w) << 16);
    *(uint2*)(out + row * 256 + col) = pk;
}

// ---------------------------------------------------------------------------
// Inconsistency + passthroughs -> d_out (FP32).
// ---------------------------------------------------------------------------
__global__ __launch_bounds__(256)
void inc_kernel(const float* __restrict__ img_sp, const float* __restrict__ txt_sp,
                const float* __restrict__ W, const float* __restrict__ bias,
                float* __restrict__ out_inc, float* __restrict__ out_img,
                float* __restrict__ out_txt)
{
    __shared__ float iv[512];
    const int b = blockIdx.x, n = threadIdx.x;
    float a = img_sp[b * 256 + n];
    float t = txt_sp[b * 256 + n];
    iv[n] = a - t;
    iv[256 + n] = a * t;
    __syncthreads();
    float acc = bias[n];
    for (int k = 0; k < 512; k++) acc += iv[k] * W[k * 256 + n];
    out_inc[b * 256 + n] = acc;
    out_img[b * 256 + n] = a;
    out_txt[b * 256 + n] = t;
}

// ---------------------------------------------------------------------------
extern "C" void kernel_launch(void* const* d_in, const int* in_sizes, int n_in,
                              void* d_out, int out_size, void* d_ws, size_t ws_size,
                              hipStream_t stream)
{
    (void)in_sizes; (void)n_in; (void)out_size; (void)ws_size;
    const float* img    = (const float*)d_in[0];
    const float* txt    = (const float*)d_in[1];
    const float* img_sp = (const float*)d_in[2];
    const float* txt_sp = (const float*)d_in[3];
    const float* wq_i = (const float*)d_in[4];  const float* bq_i = (const float*)d_in[5];
    const float* wk_i = (const float*)d_in[6];  const float* bk_i = (const float*)d_in[7];
    const float* wv_i = (const float*)d_in[8];  const float* bv_i = (const float*)d_in[9];
    const float* wo_i = (const float*)d_in[10]; const float* bo_i = (const float*)d_in[11];
    const float* wq_t = (const float*)d_in[12]; const float* bq_t = (const float*)d_in[13];
    const float* wk_t = (const float*)d_in[14]; const float* bk_t = (const float*)d_in[15];
    const float* wv_t = (const float*)d_in[16]; const float* bv_t = (const float*)d_in[17];
    const float* wo_t = (const float*)d_in[18]; const float* bo_t = (const float*)d_in[19];
    const float* lng_i = (const float*)d_in[20]; const float* lnb_i = (const float*)d_in[21];
    const float* lng_t = (const float*)d_in[22]; const float* lnb_t = (const float*)d_in[23];
    const float* enh_w = (const float*)d_in[24]; const float* enh_b = (const float*)d_in[25];
    const float* incw  = (const float*)d_in[26]; const float* incb  = (const float*)d_in[27];
    float* out = (float*)d_out;
    u16* wsp = (u16*)d_ws;
    u16* b0 = wsp;
    u16* b1 = wsp + 1 * (size_t)BUF_ELEMS;
    u16* b2 = wsp + 2 * (size_t)BUF_ELEMS;
    u16* b3 = wsp + 3 * (size_t)BUF_ELEMS;
    u16* b4 = wsp + 4 * (size_t)BUF_ELEMS;
    u16* b5 = wsp + 5 * (size_t)BUF_ELEMS;

    dim3 blk(256);
    // ---- i2t MHA: Q from img, K/V from txt ----
    gemm_f32a<<<1024, blk, 0, stream>>>(img, wq_i, bq_i, b0);
    gemm_f32a<<<1024, blk, 0, stream>>>(txt, wk_i, bk_i, b1);
    gemm_f32a<<<1024, blk, 0, stream>>>(txt, wv_i, bv_i, b2);
    attn_mfma<<<2048, blk, 0, stream>>>(b0, b1, b2, b3);
    gemm_bf16a<<<1024, blk, 0, stream>>>(b3, wo_i, bo_i, b4);
    ln_res_kernel<<<4096, blk, 0, stream>>>(b4, img, lng_i, lnb_i, b5);  // b5 = img_query
    // ---- t2i MHA: Q from txt, K/V from img ----
    gemm_f32a<<<1024, blk, 0, stream>>>(txt, wq_t, bq_t, b0);
    gemm_f32a<<<1024, blk, 0, stream>>>(img, wk_t, bk_t, b1);
    gemm_f32a<<<1024, blk, 0, stream>>>(img, wv_t, bv_t, b2);
    attn_mfma<<<2048, blk, 0, stream>>>(b0, b1, b2, b3);
    gemm_bf16a<<<1024, blk, 0, stream>>>(b3, wo_t, bo_t, b4);
    ln_res_kernel<<<4096, blk, 0, stream>>>(b4, txt, lng_t, lnb_t, b1);  // b1 = txt_query
    // ---- enhancement + inconsistency (fp32 d_out) ----
    gemm_enh<<<1024, blk, 0, stream>>>(b5, b1, enh_w, enh_b, out);
    inc_kernel<<<16, blk, 0, stream>>>(img_sp, txt_sp, incw, incb,
                                       out + 4194304, out + 4198400, out + 4202496);
}

// Round 6
// 378.353 us; speedup vs baseline: 3.7713x; 1.6399x over previous
//
#include <hip/hip_runtime.h>
#include <stdint.h>

typedef unsigned int u32;
typedef unsigned short u16;
typedef __attribute__((ext_vector_type(8))) short bf16x8;
typedef __attribute__((ext_vector_type(4))) float f32x4;

#define BUF_ELEMS (16384 * 256)

__device__ __forceinline__ float bflo(u32 u) { return __uint_as_float(u << 16); }
__device__ __forceinline__ float bfhi(u32 u) { return __uint_as_float(u & 0xffff0000u); }
__device__ __forceinline__ u16 f2bf(float f) {
    u32 u = __float_as_uint(f);
    return (u16)((u + 0x7fffu + ((u >> 16) & 1u)) >> 16);
}

// ---------------------------------------------------------------------------
// cvt: fp32 img/txt -> bf16 ws copies. grid 2048 x 256, 8 elems/thread each.
// ---------------------------------------------------------------------------
__global__ __launch_bounds__(256)
void cvt_kernel(const float* __restrict__ img, const float* __restrict__ txt,
                u16* __restrict__ oi, u16* __restrict__ ot)
{
    const size_t i = ((size_t)blockIdx.x * 256 + threadIdx.x) * 8;
    float4 a0 = *(const float4*)(img + i);
    float4 a1 = *(const float4*)(img + i + 4);
    float4 b0 = *(const float4*)(txt + i);
    float4 b1 = *(const float4*)(txt + i + 4);
    uint4 pa, pb;
    pa.x = (u32)f2bf(a0.x) | ((u32)f2bf(a0.y) << 16);
    pa.y = (u32)f2bf(a0.z) | ((u32)f2bf(a0.w) << 16);
    pa.z = (u32)f2bf(a1.x) | ((u32)f2bf(a1.y) << 16);
    pa.w = (u32)f2bf(a1.z) | ((u32)f2bf(a1.w) << 16);
    pb.x = (u32)f2bf(b0.x) | ((u32)f2bf(b0.y) << 16);
    pb.y = (u32)f2bf(b0.z) | ((u32)f2bf(b0.w) << 16);
    pb.z = (u32)f2bf(b1.x) | ((u32)f2bf(b1.y) << 16);
    pb.w = (u32)f2bf(b1.z) | ((u32)f2bf(b1.w) << 16);
    *(uint4*)(oi + i) = pa;
    *(uint4*)(ot + i) = pb;
}

// ---------------------------------------------------------------------------
// wtrans: W[k][n] fp32 -> Wt[n][k] bf16 for 9 matrices (8x [256,256] +
// enh [512,256]). 64x64 LDS tile transpose. grid 160 (16 per small, 32 enh).
// ---------------------------------------------------------------------------
struct WT {
    const float* src[9];
    u16* dst[9];
};

__global__ __launch_bounds__(256)
void wtrans_kernel(WT wt)
{
    __shared__ float T[64][65];
    const int bid = blockIdx.x, t = threadIdx.x;
    int m, sub;
    if (bid < 128) { m = bid >> 4; sub = bid & 15; }
    else           { m = 8;        sub = bid - 128; }
    const int K = (m == 8) ? 512 : 256;
    const int kt = (m == 8) ? (sub & 7) : (sub & 3);
    const int nt = (m == 8) ? (sub >> 3) : (sub >> 2);
    const int k0 = kt * 64, n0 = nt * 64;
    const float* src = wt.src[m];
    u16* dst = wt.dst[m];

    const int kk = t >> 2, nn = (t & 3) * 16;
    #pragma unroll
    for (int j = 0; j < 16; j += 4) {
        float4 v = *(const float4*)(src + (size_t)(k0 + kk) * 256 + n0 + nn + j);
        T[kk][nn + j + 0] = v.x; T[kk][nn + j + 1] = v.y;
        T[kk][nn + j + 2] = v.z; T[kk][nn + j + 3] = v.w;
    }
    __syncthreads();
    const int nn2 = t >> 2, kc = (t & 3) * 16;
    #pragma unroll
    for (int j = 0; j < 16; j++)
        dst[(size_t)(n0 + nn2) * K + k0 + kc + j] = f2bf(T[kc + j][nn2]);
}

// ---------------------------------------------------------------------------
// MFMA GEMM: C[16384,256] = concatK(A1,A2)[16384,Ksize](bf16) @ Wt^T + bias.
//   Wt is [256][Ksize] bf16 (n-major, k-contig) = B-operand layout.
//   128x128 tile, 4 waves, each wave 64x64 (4x4 frags of 16x16x32).
//   BK=64, LDS pad 72 (2-way-free ds_read_b128). grid 256 = 128 m x 2 n.
//   F32OUT: write fp32 (for enh->d_out), else bf16 ws.
// ---------------------------------------------------------------------------
template<bool F32OUT>
__global__ __launch_bounds__(256)
void gemm_mfma(const u16* __restrict__ A1, const u16* __restrict__ A2,
               const u16* __restrict__ Wt, const float* __restrict__ bias,
               void* __restrict__ Cout, int Ksize)
{
    __shared__ u16 As[128][72];
    __shared__ u16 Bs[128][72];
    const int tid = threadIdx.x;
    const int wave = tid >> 6, lane = tid & 63;
    const int L = lane & 15, Qd = lane >> 4;
    const int m0 = (blockIdx.x >> 1) * 128;
    const int n0 = (blockIdx.x & 1) * 128;
    const int wr = wave & 1, wc = wave >> 1;
    const int sr = tid >> 1, sh = (tid & 1) * 32;

    f32x4 acc[4][4] = {};

    for (int kt = 0; kt < Ksize; kt += 64) {
        const u16* Asrc = (kt < 256) ? A1 : A2;
        const u16* Ap = Asrc + (size_t)(m0 + sr) * 256 + (kt & 255) + sh;
        const u16* Bp = Wt + (size_t)(n0 + sr) * Ksize + kt + sh;
        uint4 a0 = *(const uint4*)(Ap + 0);
        uint4 a1 = *(const uint4*)(Ap + 8);
        uint4 a2 = *(const uint4*)(Ap + 16);
        uint4 a3 = *(const uint4*)(Ap + 24);
        uint4 w0 = *(const uint4*)(Bp + 0);
        uint4 w1 = *(const uint4*)(Bp + 8);
        uint4 w2 = *(const uint4*)(Bp + 16);
        uint4 w3 = *(const uint4*)(Bp + 24);
        *(uint4*)&As[sr][sh + 0]  = a0;
        *(uint4*)&As[sr][sh + 8]  = a1;
        *(uint4*)&As[sr][sh + 16] = a2;
        *(uint4*)&As[sr][sh + 24] = a3;
        *(uint4*)&Bs[sr][sh + 0]  = w0;
        *(uint4*)&Bs[sr][sh + 8]  = w1;
        *(uint4*)&Bs[sr][sh + 16] = w2;
        *(uint4*)&Bs[sr][sh + 24] = w3;
        __syncthreads();
        #pragma unroll
        for (int kh = 0; kh < 64; kh += 32) {
            bf16x8 af[4], bf[4];
            #pragma unroll
            for (int mt = 0; mt < 4; mt++)
                af[mt] = *(const bf16x8*)&As[wr * 64 + mt * 16 + L][kh + Qd * 8];
            #pragma unroll
            for (int nt = 0; nt < 4; nt++)
                bf[nt] = *(const bf16x8*)&Bs[wc * 64 + nt * 16 + L][kh + Qd * 8];
            #pragma unroll
            for (int mt = 0; mt < 4; mt++)
                #pragma unroll
                for (int nt = 0; nt < 4; nt++)
                    acc[mt][nt] = __builtin_amdgcn_mfma_f32_16x16x32_bf16(
                        af[mt], bf[nt], acc[mt][nt], 0, 0, 0);
        }
        __syncthreads();
    }

    float bvals[4];
    #pragma unroll
    for (int nt = 0; nt < 4; nt++)
        bvals[nt] = bias[n0 + wc * 64 + nt * 16 + L];
    #pragma unroll
    for (int mt = 0; mt < 4; mt++) {
        #pragma unroll
        for (int r = 0; r < 4; r++) {
            const size_t row = (size_t)(m0 + wr * 64 + mt * 16 + Qd * 4 + r) * 256;
            #pragma unroll
            for (int nt = 0; nt < 4; nt++) {
                const int col = n0 + wc * 64 + nt * 16 + L;
                float v = acc[mt][nt][r] + bvals[nt];
                if (F32OUT) ((float*)Cout)[row + col] = v;
                else        ((u16*)Cout)[row + col] = f2bf(v);
            }
        }
    }
}

// ---------------------------------------------------------------------------
// MFMA flash attention (unchanged from round 5; 73.6 us each).
// ---------------------------------------------------------------------------
__global__ __launch_bounds__(256)
void attn_mfma(const u16* __restrict__ Q, const u16* __restrict__ K,
               const u16* __restrict__ V, u16* __restrict__ O)
{
    __shared__ u16 Ks[128][40];
    __shared__ u16 Vt[32][136];
    __shared__ u16 Ps[4][16][136];
    const int tid = threadIdx.x;
    const int wave = tid >> 6, lane = tid & 63;
    const int L = lane & 15, Qd = lane >> 4;
    const int qt = blockIdx.x & 15;
    const int h = (blockIdx.x >> 4) & 7;
    const int b = blockIdx.x >> 7;
    const int rowbase = b * 1024;
    const float sc2 = 0.17677669529663687f * 1.4426950408889634f;

    const int qrow = rowbase + qt * 64 + wave * 16 + L;
    bf16x8 qfrag = *(const bf16x8*)(Q + (size_t)qrow * 256 + h * 32 + Qd * 8);

    f32x4 oacc0 = {0.f, 0.f, 0.f, 0.f};
    f32x4 oacc1 = {0.f, 0.f, 0.f, 0.f};
    float lpart[4] = {0.f, 0.f, 0.f, 0.f};

    const int sr = tid >> 1;
    const int scol = (tid & 1) * 16;

    for (int t = 0; t < 8; t++) {
        const size_t kvbase = (size_t)(rowbase + t * 128 + sr) * 256 + h * 32 + scol;
        uint4 k1 = *(const uint4*)(K + kvbase);
        uint4 k2 = *(const uint4*)(K + kvbase + 8);
        uint4 v1 = *(const uint4*)(V + kvbase);
        uint4 v2 = *(const uint4*)(V + kvbase + 8);
        *(uint4*)&Ks[sr][scol]     = k1;
        *(uint4*)&Ks[sr][scol + 8] = k2;
        union { uint4 u4[2]; u16 us[16]; } vv;
        vv.u4[0] = v1; vv.u4[1] = v2;
        #pragma unroll
        for (int j = 0; j < 16; j++) Vt[scol + j][sr] = vv.us[j];
        __syncthreads();

        const f32x4 z = {0.f, 0.f, 0.f, 0.f};
        f32x4 sacc[8];
        #pragma unroll
        for (int ct = 0; ct < 8; ct++) {
            bf16x8 kfrag = *(const bf16x8*)&Ks[ct * 16 + L][Qd * 8];
            sacc[ct] = __builtin_amdgcn_mfma_f32_16x16x32_bf16(qfrag, kfrag, z, 0, 0, 0);
        }
        #pragma unroll
        for (int ct = 0; ct < 8; ct++) {
            #pragma unroll
            for (int r = 0; r < 4; r++) {
                float p = exp2f(sacc[ct][r] * sc2);
                lpart[r] += p;
                Ps[wave][Qd * 4 + r][ct * 16 + L] = f2bf(p);
            }
        }
        #pragma unroll
        for (int kc = 0; kc < 4; kc++) {
            bf16x8 pfrag = *(const bf16x8*)&Ps[wave][L][kc * 32 + Qd * 8];
            bf16x8 vf0 = *(const bf16x8*)&Vt[L][kc * 32 + Qd * 8];
            bf16x8 vf1 = *(const bf16x8*)&Vt[16 + L][kc * 32 + Qd * 8];
            oacc0 = __builtin_amdgcn_mfma_f32_16x16x32_bf16(pfrag, vf0, oacc0, 0, 0, 0);
            oacc1 = __builtin_amdgcn_mfma_f32_16x16x32_bf16(pfrag, vf1, oacc1, 0, 0, 0);
        }
        __syncthreads();
    }

    #pragma unroll
    for (int r = 0; r < 4; r++) {
        float v = lpart[r];
        v += __shfl_xor(v, 1); v += __shfl_xor(v, 2);
        v += __shfl_xor(v, 4); v += __shfl_xor(v, 8);
        lpart[r] = 1.f / v;
    }
    #pragma unroll
    for (int r = 0; r < 4; r++) {
        const size_t orow = (size_t)(rowbase + qt * 64 + wave * 16 + Qd * 4 + r) * 256 + h * 32;
        O[orow + L]      = f2bf(oacc0[r] * lpart[r]);
        O[orow + 16 + L] = f2bf(oacc1[r] * lpart[r]);
    }
}

// ---------------------------------------------------------------------------
// Residual + LayerNorm: out(bf16 ws) = LN(P(bf16) + R(fp32)) * g + beta.
// ---------------------------------------------------------------------------
__global__ __launch_bounds__(256)
void ln_res_kernel(const u16* __restrict__ P, const float* __restrict__ R,
                   const float* __restrict__ g, const float* __restrict__ beta,
                   u16* __restrict__ out)
{
    const int lane = threadIdx.x & 63;
    const int row = blockIdx.x * 4 + (threadIdx.x >> 6);
    const int col = lane * 4;
    uint2 pv = *(const uint2*)(P + row * 256 + col);
    float4 rv = *(const float4*)(R + row * 256 + col);
    float x0 = bflo(pv.x) + rv.x;
    float x1 = bfhi(pv.x) + rv.y;
    float x2 = bflo(pv.y) + rv.z;
    float x3 = bfhi(pv.y) + rv.w;
    float s = x0 + x1 + x2 + x3;
    float s2 = x0*x0 + x1*x1 + x2*x2 + x3*x3;
    #pragma unroll
    for (int off = 32; off > 0; off >>= 1) {
        s  += __shfl_xor(s, off);
        s2 += __shfl_xor(s2, off);
    }
    float mean = s * 0.00390625f;
    float var = fmaxf(s2 * 0.00390625f - mean * mean, 0.f);
    float rstd = rsqrtf(var + 1e-5f);
    float4 gv = *(const float4*)(g + col);
    float4 bv = *(const float4*)(beta + col);
    uint2 pk;
    pk.x = (u32)f2bf((x0 - mean) * rstd * gv.x + bv.x)
         | ((u32)f2bf((x1 - mean) * rstd * gv.y + bv.y) << 16);
    pk.y = (u32)f2bf((x2 - mean) * rstd * gv.z + bv.z)
         | ((u32)f2bf((x3 - mean) * rstd * gv.w + bv.w) << 16);
    *(uint2*)(out + row * 256 + col) = pk;
}

// ---------------------------------------------------------------------------
// Inconsistency + passthroughs -> d_out (FP32).
// ---------------------------------------------------------------------------
__global__ __launch_bounds__(256)
void inc_kernel(const float* __restrict__ img_sp, const float* __restrict__ txt_sp,
                const float* __restrict__ W, const float* __restrict__ bias,
                float* __restrict__ out_inc, float* __restrict__ out_img,
                float* __restrict__ out_txt)
{
    __shared__ float iv[512];
    const int b = blockIdx.x, n = threadIdx.x;
    float a = img_sp[b * 256 + n];
    float t = txt_sp[b * 256 + n];
    iv[n] = a - t;
    iv[256 + n] = a * t;
    __syncthreads();
    float acc = bias[n];
    for (int k = 0; k < 512; k++) acc += iv[k] * W[k * 256 + n];
    out_inc[b * 256 + n] = acc;
    out_img[b * 256 + n] = a;
    out_txt[b * 256 + n] = t;
}

// ---------------------------------------------------------------------------
extern "C" void kernel_launch(void* const* d_in, const int* in_sizes, int n_in,
                              void* d_out, int out_size, void* d_ws, size_t ws_size,
                              hipStream_t stream)
{
    (void)in_sizes; (void)n_in; (void)out_size; (void)ws_size;
    const float* img    = (const float*)d_in[0];
    const float* txt    = (const float*)d_in[1];
    const float* img_sp = (const float*)d_in[2];
    const float* txt_sp = (const float*)d_in[3];
    const float* wq_i = (const float*)d_in[4];  const float* bq_i = (const float*)d_in[5];
    const float* wk_i = (const float*)d_in[6];  const float* bk_i = (const float*)d_in[7];
    const float* wv_i = (const float*)d_in[8];  const float* bv_i = (const float*)d_in[9];
    const float* wo_i = (const float*)d_in[10]; const float* bo_i = (const float*)d_in[11];
    const float* wq_t = (const float*)d_in[12]; const float* bq_t = (const float*)d_in[13];
    const float* wk_t = (const float*)d_in[14]; const float* bk_t = (const float*)d_in[15];
    const float* wv_t = (const float*)d_in[16]; const float* bv_t = (const float*)d_in[17];
    const float* wo_t = (const float*)d_in[18]; const float* bo_t = (const float*)d_in[19];
    const float* lng_i = (const float*)d_in[20]; const float* lnb_i = (const float*)d_in[21];
    const float* lng_t = (const float*)d_in[22]; const float* lnb_t = (const float*)d_in[23];
    const float* enh_w = (const float*)d_in[24]; const float* enh_b = (const float*)d_in[25];
    const float* incw  = (const float*)d_in[26]; const float* incb  = (const float*)d_in[27];
    float* out = (float*)d_out;
    u16* wsp = (u16*)d_ws;
    // S0..S5: 8 MB bf16 work buffers; weight area after them (~1.3 MB).
    u16* S0 = wsp;                              // p_img -> (t2i attn out)
    u16* S1 = wsp + 1 * (size_t)BUF_ELEMS;      // p_txt -> txt_query
    u16* S2 = wsp + 2 * (size_t)BUF_ELEMS;      // Q / proj out
    u16* S3 = wsp + 3 * (size_t)BUF_ELEMS;      // Ki -> img_query
    u16* S4 = wsp + 4 * (size_t)BUF_ELEMS;      // Vi / Kt
    u16* S5 = wsp + 5 * (size_t)BUF_ELEMS;      // AOi / Vt
    u16* wbase = wsp + 6 * (size_t)BUF_ELEMS;
    u16* Wt_qi = wbase + 0 * 65536;
    u16* Wt_ki = wbase + 1 * 65536;
    u16* Wt_vi = wbase + 2 * 65536;
    u16* Wt_oi = wbase + 3 * 65536;
    u16* Wt_qt = wbase + 4 * 65536;
    u16* Wt_kt = wbase + 5 * 65536;
    u16* Wt_vt = wbase + 6 * 65536;
    u16* Wt_ot = wbase + 7 * 65536;
    u16* Wt_en = wbase + 8 * 65536;             // [256][512]

    dim3 blk(256);
    // ---- prep: bf16 inputs + transposed bf16 weights ----
    cvt_kernel<<<2048, blk, 0, stream>>>(img, txt, S0, S1);
    WT wt;
    wt.src[0] = wq_i; wt.src[1] = wk_i; wt.src[2] = wv_i; wt.src[3] = wo_i;
    wt.src[4] = wq_t; wt.src[5] = wk_t; wt.src[6] = wv_t; wt.src[7] = wo_t;
    wt.src[8] = enh_w;
    wt.dst[0] = Wt_qi; wt.dst[1] = Wt_ki; wt.dst[2] = Wt_vi; wt.dst[3] = Wt_oi;
    wt.dst[4] = Wt_qt; wt.dst[5] = Wt_kt; wt.dst[6] = Wt_vt; wt.dst[7] = Wt_ot;
    wt.dst[8] = Wt_en;
    wtrans_kernel<<<160, blk, 0, stream>>>(wt);

    // ---- i2t MHA: Q from img, K/V from txt ----
    gemm_mfma<false><<<256, blk, 0, stream>>>(S0, S0, Wt_qi, bq_i, S2, 256);
    gemm_mfma<false><<<256, blk, 0, stream>>>(S1, S1, Wt_ki, bk_i, S3, 256);
    gemm_mfma<false><<<256, blk, 0, stream>>>(S1, S1, Wt_vi, bv_i, S4, 256);
    attn_mfma<<<2048, blk, 0, stream>>>(S2, S3, S4, S5);
    gemm_mfma<false><<<256, blk, 0, stream>>>(S5, S5, Wt_oi, bo_i, S2, 256);
    ln_res_kernel<<<4096, blk, 0, stream>>>(S2, img, lng_i, lnb_i, S3);   // S3 = img_query
    // ---- t2i MHA: Q from txt, K/V from img ----
    gemm_mfma<false><<<256, blk, 0, stream>>>(S1, S1, Wt_qt, bq_t, S2, 256);
    gemm_mfma<false><<<256, blk, 0, stream>>>(S0, S0, Wt_kt, bk_t, S4, 256);
    gemm_mfma<false><<<256, blk, 0, stream>>>(S0, S0, Wt_vt, bv_t, S5, 256);
    attn_mfma<<<2048, blk, 0, stream>>>(S2, S4, S5, S0);
    gemm_mfma<false><<<256, blk, 0, stream>>>(S0, S0, Wt_ot, bo_t, S2, 256);
    ln_res_kernel<<<4096, blk, 0, stream>>>(S2, txt, lng_t, lnb_t, S1);   // S1 = txt_query
    // ---- enhancement (concat-K GEMM, fp32 out) + inconsistency ----
    gemm_mfma<true><<<256, blk, 0, stream>>>(S3, S1, Wt_en, enh_b, out, 512);
    inc_kernel<<<16, blk, 0, stream>>>(img_sp, txt_sp, incw, incb,
                                       out + 4194304, out + 4198400, out + 4202496);
}

// Round 7
// 334.920 us; speedup vs baseline: 4.2604x; 1.1297x over previous
//
#include <hip/hip_runtime.h>
#include <stdint.h>

typedef unsigned int u32;
typedef unsigned short u16;
typedef __attribute__((ext_vector_type(8))) short bf16x8;
typedef __attribute__((ext_vector_type(4))) float f32x4;

#define BUF_ELEMS (16384 * 256)

__device__ __forceinline__ float bflo(u32 u) { return __uint_as_float(u << 16); }
__device__ __forceinline__ float bfhi(u32 u) { return __uint_as_float(u & 0xffff0000u); }
__device__ __forceinline__ u16 f2bf(float f) {
    u32 u = __float_as_uint(f);
    return (u16)((u + 0x7fffu + ((u >> 16) & 1u)) >> 16);
}
// pack high halves of two f32 -> u32 (truncation-round bf16 pair, lo first)
__device__ __forceinline__ u32 pkhi(float lo, float hi) {
    return __builtin_amdgcn_perm(__float_as_uint(hi), __float_as_uint(lo), 0x07060302u);
}

// ---------------------------------------------------------------------------
// wtrans: 9x W[k][n] fp32 -> Wt[n][k] bf16 (dst ptrs pre-offset; stride=K),
// plus block 160 builds concatenated QKV bias arrays.
// ---------------------------------------------------------------------------
struct WT {
    const float* src[9];
    u16* dst[9];
    const float* bs[6];   // bq_i, bk_t, bv_t, bq_t, bk_i, bv_i
    float* bA;            // [768]
    float* bB;            // [768]
};

__global__ __launch_bounds__(256)
void wtrans_kernel(WT wt)
{
    __shared__ float T[64][65];
    const int bid = blockIdx.x, t = threadIdx.x;
    if (bid == 160) {
        if (t < 256) {
            wt.bA[t]       = wt.bs[0][t];
            wt.bA[256 + t] = wt.bs[1][t];
            wt.bA[512 + t] = wt.bs[2][t];
            wt.bB[t]       = wt.bs[3][t];
            wt.bB[256 + t] = wt.bs[4][t];
            wt.bB[512 + t] = wt.bs[5][t];
        }
        return;
    }
    int m, sub;
    if (bid < 128) { m = bid >> 4; sub = bid & 15; }
    else           { m = 8;        sub = bid - 128; }
    const int K = (m == 8) ? 512 : 256;
    const int kt = (m == 8) ? (sub & 7) : (sub & 3);
    const int nt = (m == 8) ? (sub >> 3) : (sub >> 2);
    const int k0 = kt * 64, n0 = nt * 64;
    const float* src = wt.src[m];
    u16* dst = wt.dst[m];

    const int kk = t >> 2, nn = (t & 3) * 16;
    #pragma unroll
    for (int j = 0; j < 16; j += 4) {
        float4 v = *(const float4*)(src + (size_t)(k0 + kk) * 256 + n0 + nn + j);
        T[kk][nn + j + 0] = v.x; T[kk][nn + j + 1] = v.y;
        T[kk][nn + j + 2] = v.z; T[kk][nn + j + 3] = v.w;
    }
    __syncthreads();
    const int nn2 = t >> 2, kc = (t & 3) * 16;
    #pragma unroll
    for (int j = 0; j < 16; j++)
        dst[(size_t)(n0 + nn2) * K + k0 + kc + j] = f2bf(T[kc + j][nn2]);
}

// ---------------------------------------------------------------------------
// Unified MFMA GEMM. 128x128 tile, 4 waves (2x2 of 64x64), BK=64.
// MODE 0 QKV : A fp32 (in-register cvt), N=768, K=256, out ptr by n-group.
// MODE 1 OPRJ: A bf16, M=32768 m-stacked (A/W/bias/out selected by m0), N=256.
// MODE 2 ENH : A bf16 x2 kt-concat (K=512), N=256, fp32 out.
// ---------------------------------------------------------------------------
template<int MODE>
__global__ __launch_bounds__(256)
void gemm_mfma(const float* __restrict__ Af,
               const u16* __restrict__ Ab0, const u16* __restrict__ Ab1,
               const u16* __restrict__ Wt0, const u16* __restrict__ Wt1,
               const float* __restrict__ bias0, const float* __restrict__ bias1,
               void* __restrict__ o0, void* __restrict__ o1, void* __restrict__ o2)
{
    __shared__ u16 As[128][72];
    __shared__ u16 Bs[128][72];
    const int tid = threadIdx.x;
    const int wave = tid >> 6, lane = tid & 63;
    const int L = lane & 15, Qd = lane >> 4;
    int m0, n0;
    if (MODE == 0) { n0 = (blockIdx.x % 6) * 128; m0 = (blockIdx.x / 6) * 128; }
    else           { n0 = (blockIdx.x & 1) * 128; m0 = (blockIdx.x >> 1) * 128; }
    const bool msel = (MODE == 1) && (m0 >= 16384);
    const int lm0 = msel ? (m0 - 16384) : m0;
    const u16* Wt = (MODE == 1 && msel) ? Wt1 : Wt0;
    const float* bias = (MODE == 1 && msel) ? bias1 : bias0;
    const int wr = wave & 1, wc = wave >> 1;
    const int sr = tid >> 1, sh = (tid & 1) * 32;
    const int KS = (MODE == 2) ? 512 : 256;

    f32x4 acc[4][4] = {};

    for (int kt = 0; kt < KS; kt += 64) {
        // ---- stage A ----
        if (MODE == 0) {
            const float* Ap = Af + (size_t)(m0 + sr) * 256 + kt + sh;
            uint4 pk[2];
            #pragma unroll
            for (int half = 0; half < 2; half++) {
                float4 f0 = *(const float4*)(Ap + half * 16);
                float4 f1 = *(const float4*)(Ap + half * 16 + 4);
                float4 f2 = *(const float4*)(Ap + half * 16 + 8);
                float4 f3 = *(const float4*)(Ap + half * 16 + 12);
                pk[half].x = pkhi(f0.x, f0.y);
                pk[half].y = pkhi(f0.z, f0.w);
                pk[half].z = pkhi(f1.x, f1.y);
                pk[half].w = pkhi(f1.z, f1.w);
                uint4 q;
                q.x = pkhi(f2.x, f2.y); q.y = pkhi(f2.z, f2.w);
                q.z = pkhi(f3.x, f3.y); q.w = pkhi(f3.z, f3.w);
                *(uint4*)&As[sr][sh + half * 16 + 8] = q;
            }
            *(uint4*)&As[sr][sh + 0] = pk[0];
            *(uint4*)&As[sr][sh + 16] = pk[1];
        } else {
            const u16* Abase;
            int lkt = kt;
            if (MODE == 2) { Abase = (kt < 256) ? Ab0 : Ab1; lkt = kt & 255; }
            else           { Abase = msel ? Ab1 : Ab0; }
            const u16* Ap = Abase + (size_t)(lm0 + sr) * 256 + lkt + sh;
            uint4 a0 = *(const uint4*)(Ap + 0);
            uint4 a1 = *(const uint4*)(Ap + 8);
            uint4 a2 = *(const uint4*)(Ap + 16);
            uint4 a3 = *(const uint4*)(Ap + 24);
            *(uint4*)&As[sr][sh + 0]  = a0;
            *(uint4*)&As[sr][sh + 8]  = a1;
            *(uint4*)&As[sr][sh + 16] = a2;
            *(uint4*)&As[sr][sh + 24] = a3;
        }
        // ---- stage B (Wt is n-major [n][k], stride KS) ----
        {
            const u16* Bp = Wt + (size_t)(n0 + sr) * KS + kt + sh;
            uint4 w0 = *(const uint4*)(Bp + 0);
            uint4 w1 = *(const uint4*)(Bp + 8);
            uint4 w2 = *(const uint4*)(Bp + 16);
            uint4 w3 = *(const uint4*)(Bp + 24);
            *(uint4*)&Bs[sr][sh + 0]  = w0;
            *(uint4*)&Bs[sr][sh + 8]  = w1;
            *(uint4*)&Bs[sr][sh + 16] = w2;
            *(uint4*)&Bs[sr][sh + 24] = w3;
        }
        __syncthreads();
        #pragma unroll
        for (int kh = 0; kh < 64; kh += 32) {
            bf16x8 af[4], bf[4];
            #pragma unroll
            for (int mt = 0; mt < 4; mt++)
                af[mt] = *(const bf16x8*)&As[wr * 64 + mt * 16 + L][kh + Qd * 8];
            #pragma unroll
            for (int nt = 0; nt < 4; nt++)
                bf[nt] = *(const bf16x8*)&Bs[wc * 64 + nt * 16 + L][kh + Qd * 8];
            #pragma unroll
            for (int mt = 0; mt < 4; mt++)
                #pragma unroll
                for (int nt = 0; nt < 4; nt++)
                    acc[mt][nt] = __builtin_amdgcn_mfma_f32_16x16x32_bf16(
                        af[mt], bf[nt], acc[mt][nt], 0, 0, 0);
        }
        __syncthreads();
    }

    // ---- epilogue ----
    float bvals[4];
    #pragma unroll
    for (int nt = 0; nt < 4; nt++)
        bvals[nt] = bias[n0 + wc * 64 + nt * 16 + L];

    void* outp;
    int colb;
    if (MODE == 0) {
        const int g = n0 >> 8;
        outp = (g == 0) ? o0 : ((g == 1) ? o1 : o2);
        colb = (n0 & 255) + wc * 64;
    } else if (MODE == 1) {
        outp = msel ? o1 : o0;
        colb = n0 + wc * 64;
    } else {
        outp = o0;
        colb = n0 + wc * 64;
    }
    #pragma unroll
    for (int mt = 0; mt < 4; mt++) {
        #pragma unroll
        for (int r = 0; r < 4; r++) {
            const size_t row = (size_t)(lm0 + wr * 64 + mt * 16 + Qd * 4 + r) * 256;
            #pragma unroll
            for (int nt = 0; nt < 4; nt++) {
                const int col = colb + nt * 16 + L;
                float v = acc[mt][nt][r] + bvals[nt];
                if (MODE == 2) ((float*)outp)[row + col] = v;
                else           ((u16*)outp)[row + col] = f2bf(v);
            }
        }
    }
}

// ---------------------------------------------------------------------------
// MFMA flash attention, both sets in one dispatch. 128 q-rows/block (2 sub-
// tiles of 64), K-tile 128 keys. Virtual key order v=(key&15)*8+(key>>4):
// P-writes become ds_write_b128 and f2bf becomes v_perm truncation packs.
// Output written in-place over Q (block-exclusive (q-rows, head-cols)).
// grid 2048 = 2 sets * 16 b * 8 h * 8 qt; block 256.
// ---------------------------------------------------------------------------
__global__ __launch_bounds__(256)
void attn_mfma(const u16* __restrict__ Q0, const u16* __restrict__ K0,
               const u16* __restrict__ V0, u16* __restrict__ O0,
               const u16* __restrict__ Q1, const u16* __restrict__ K1,
               const u16* __restrict__ V1, u16* __restrict__ O1)
{
    __shared__ u16 Ks[128][40];      // [key][dim]
    __shared__ u16 Vt[32][136];      // [dim][v-key]
    __shared__ u16 Ps[8][16][136];   // [wave*2+qs][q][v-key]
    const int tid = threadIdx.x;
    const int wave = tid >> 6, lane = tid & 63;
    const int L = lane & 15, Qd = lane >> 4;
    const int bid = blockIdx.x;
    const int set = bid >> 10;
    const int r3 = bid & 1023;
    const int qt = r3 & 7;
    const int h = (r3 >> 3) & 7;
    const int b = r3 >> 6;
    const u16* Q = set ? Q1 : Q0;
    const u16* K = set ? K1 : K0;
    const u16* V = set ? V1 : V0;
    u16* O = set ? O1 : O0;
    const int rowbase = b * 1024;
    const int qbase = rowbase + qt * 128;
    const float sc2 = 0.17677669529663687f * 1.4426950408889634f;

    bf16x8 qfrag[2];
    #pragma unroll
    for (int qs = 0; qs < 2; qs++)
        qfrag[qs] = *(const bf16x8*)(Q + (size_t)(qbase + qs * 64 + wave * 16 + L) * 256
                                       + h * 32 + Qd * 8);

    f32x4 oacc[2][2] = {};
    float lpart[2][4] = {};

    const int sr = tid >> 1;          // key 0..127
    const int scol = (tid & 1) * 16;  // dim half
    const int vcol = (sr & 15) * 8 + (sr >> 4);

    for (int t = 0; t < 8; t++) {
        const size_t kvbase = (size_t)(rowbase + t * 128 + sr) * 256 + h * 32 + scol;
        uint4 k1 = *(const uint4*)(K + kvbase);
        uint4 k2 = *(const uint4*)(K + kvbase + 8);
        uint4 v1 = *(const uint4*)(V + kvbase);
        uint4 v2 = *(const uint4*)(V + kvbase + 8);
        *(uint4*)&Ks[sr][scol]     = k1;
        *(uint4*)&Ks[sr][scol + 8] = k2;
        union { uint4 u4[2]; u16 us[16]; } vv;
        vv.u4[0] = v1; vv.u4[1] = v2;
        #pragma unroll
        for (int j = 0; j < 16; j++) Vt[scol + j][vcol] = vv.us[j];
        __syncthreads();

        #pragma unroll
        for (int qs = 0; qs < 2; qs++) {
            const int w2 = wave * 2 + qs;
            const f32x4 z = {0.f, 0.f, 0.f, 0.f};
            f32x4 sacc[8];
            #pragma unroll
            for (int ct = 0; ct < 8; ct++) {
                bf16x8 kfrag = *(const bf16x8*)&Ks[ct * 16 + L][Qd * 8];
                sacc[ct] = __builtin_amdgcn_mfma_f32_16x16x32_bf16(qfrag[qs], kfrag, z, 0, 0, 0);
            }
            #pragma unroll
            for (int r = 0; r < 4; r++) {
                float p[8];
                #pragma unroll
                for (int ct = 0; ct < 8; ct++) {
                    p[ct] = exp2f(sacc[ct][r] * sc2);
                    lpart[qs][r] += p[ct];
                }
                uint4 pk;
                pk.x = pkhi(p[0], p[1]);
                pk.y = pkhi(p[2], p[3]);
                pk.z = pkhi(p[4], p[5]);
                pk.w = pkhi(p[6], p[7]);
                *(uint4*)&Ps[w2][Qd * 4 + r][L * 8] = pk;
            }
            #pragma unroll
            for (int kc = 0; kc < 4; kc++) {
                bf16x8 pfrag = *(const bf16x8*)&Ps[w2][L][kc * 32 + Qd * 8];
                bf16x8 vf0 = *(const bf16x8*)&Vt[L][kc * 32 + Qd * 8];
                bf16x8 vf1 = *(const bf16x8*)&Vt[16 + L][kc * 32 + Qd * 8];
                oacc[qs][0] = __builtin_amdgcn_mfma_f32_16x16x32_bf16(pfrag, vf0, oacc[qs][0], 0, 0, 0);
                oacc[qs][1] = __builtin_amdgcn_mfma_f32_16x16x32_bf16(pfrag, vf1, oacc[qs][1], 0, 0, 0);
            }
        }
        __syncthreads();
    }

    #pragma unroll
    for (int qs = 0; qs < 2; qs++) {
        #pragma unroll
        for (int r = 0; r < 4; r++) {
            float v = lpart[qs][r];
            v += __shfl_xor(v, 1); v += __shfl_xor(v, 2);
            v += __shfl_xor(v, 4); v += __shfl_xor(v, 8);
            float inv = 1.f / v;
            const size_t orow = (size_t)(qbase + qs * 64 + wave * 16 + Qd * 4 + r) * 256 + h * 32;
            O[orow + L]      = f2bf(oacc[qs][0][r] * inv);
            O[orow + 16 + L] = f2bf(oacc[qs][1][r] * inv);
        }
    }
}

// ---------------------------------------------------------------------------
// Residual + LayerNorm, both halves: rows<16384 -> (P0, img) -> out0;
// rows>=16384 -> (P1, txt) -> out1. One wave per row.
// ---------------------------------------------------------------------------
__global__ __launch_bounds__(256)
void ln_res_kernel(const u16* __restrict__ P0, const u16* __restrict__ P1,
                   const float* __restrict__ R0, const float* __restrict__ R1,
                   const float* __restrict__ g0, const float* __restrict__ be0,
                   const float* __restrict__ g1, const float* __restrict__ be1,
                   u16* __restrict__ out0, u16* __restrict__ out1)
{
    const int lane = threadIdx.x & 63;
    int row = blockIdx.x * 4 + (threadIdx.x >> 6);
    const bool sel = row >= 16384;
    const u16* P = sel ? P1 : P0;
    const float* R = sel ? R1 : R0;
    const float* g = sel ? g1 : g0;
    const float* be = sel ? be1 : be0;
    u16* out = sel ? out1 : out0;
    if (sel) row -= 16384;
    const int col = lane * 4;
    uint2 pv = *(const uint2*)(P + (size_t)row * 256 + col);
    float4 rv = *(const float4*)(R + (size_t)row * 256 + col);
    float x0 = bflo(pv.x) + rv.x;
    float x1 = bfhi(pv.x) + rv.y;
    float x2 = bflo(pv.y) + rv.z;
    float x3 = bfhi(pv.y) + rv.w;
    float s = x0 + x1 + x2 + x3;
    float s2 = x0*x0 + x1*x1 + x2*x2 + x3*x3;
    #pragma unroll
    for (int off = 32; off > 0; off >>= 1) {
        s  += __shfl_xor(s, off);
        s2 += __shfl_xor(s2, off);
    }
    float mean = s * 0.00390625f;
    float var = fmaxf(s2 * 0.00390625f - mean * mean, 0.f);
    float rstd = rsqrtf(var + 1e-5f);
    float4 gv = *(const float4*)(g + col);
    float4 bv = *(const float4*)(be + col);
    uint2 pk;
    pk.x = (u32)f2bf((x0 - mean) * rstd * gv.x + bv.x)
         | ((u32)f2bf((x1 - mean) * rstd * gv.y + bv.y) << 16);
    pk.y = (u32)f2bf((x2 - mean) * rstd * gv.z + bv.z)
         | ((u32)f2bf((x3 - mean) * rstd * gv.w + bv.w) << 16);
    *(uint2*)(out + (size_t)row * 256 + col) = pk;
}

// ---------------------------------------------------------------------------
// Inconsistency + passthroughs -> d_out (FP32).
// ---------------------------------------------------------------------------
__global__ __launch_bounds__(256)
void inc_kernel(const float* __restrict__ img_sp, const float* __restrict__ txt_sp,
                const float* __restrict__ W, const float* __restrict__ bias,
                float* __restrict__ out_inc, float* __restrict__ out_img,
                float* __restrict__ out_txt)
{
    __shared__ float iv[512];
    const int b = blockIdx.x, n = threadIdx.x;
    float a = img_sp[b * 256 + n];
    float t = txt_sp[b * 256 + n];
    iv[n] = a - t;
    iv[256 + n] = a * t;
    __syncthreads();
    float acc = bias[n];
    for (int k = 0; k < 512; k++) acc += iv[k] * W[k * 256 + n];
    out_inc[b * 256 + n] = acc;
    out_img[b * 256 + n] = a;
    out_txt[b * 256 + n] = t;
}

// ---------------------------------------------------------------------------
extern "C" void kernel_launch(void* const* d_in, const int* in_sizes, int n_in,
                              void* d_out, int out_size, void* d_ws, size_t ws_size,
                              hipStream_t stream)
{
    (void)in_sizes; (void)n_in; (void)out_size; (void)ws_size;
    const float* img    = (const float*)d_in[0];
    const float* txt    = (const float*)d_in[1];
    const float* img_sp = (const float*)d_in[2];
    const float* txt_sp = (const float*)d_in[3];
    const float* wq_i = (const float*)d_in[4];  const float* bq_i = (const float*)d_in[5];
    const float* wk_i = (const float*)d_in[6];  const float* bk_i = (const float*)d_in[7];
    const float* wv_i = (const float*)d_in[8];  const float* bv_i = (const float*)d_in[9];
    const float* wo_i = (const float*)d_in[10]; const float* bo_i = (const float*)d_in[11];
    const float* wq_t = (const float*)d_in[12]; const float* bq_t = (const float*)d_in[13];
    const float* wk_t = (const float*)d_in[14]; const float* bk_t = (const float*)d_in[15];
    const float* wv_t = (const float*)d_in[16]; const float* bv_t = (const float*)d_in[17];
    const float* wo_t = (const float*)d_in[18]; const float* bo_t = (const float*)d_in[19];
    const float* lng_i = (const float*)d_in[20]; const float* lnb_i = (const float*)d_in[21];
    const float* lng_t = (const float*)d_in[22]; const float* lnb_t = (const float*)d_in[23];
    const float* enh_w = (const float*)d_in[24]; const float* enh_b = (const float*)d_in[25];
    const float* incw  = (const float*)d_in[26]; const float* incb  = (const float*)d_in[27];
    float* out = (float*)d_out;
    u16* wsp = (u16*)d_ws;
    // B0..B5 (8MB each):
    // B0: Q_i2t -> AO_i2t (in-place)        B3: Q_t2i -> AO_t2i (in-place)
    // B1: K_i2t -> proj_i2t                 B4: K_t2i -> proj_t2i
    // B2: V_i2t -> img_query                B5: V_t2i -> txt_query
    u16* B0 = wsp;
    u16* B1 = wsp + 1 * (size_t)BUF_ELEMS;
    u16* B2 = wsp + 2 * (size_t)BUF_ELEMS;
    u16* B3 = wsp + 3 * (size_t)BUF_ELEMS;
    u16* B4 = wsp + 4 * (size_t)BUF_ELEMS;
    u16* B5 = wsp + 5 * (size_t)BUF_ELEMS;
    u16* wbase = wsp + 6 * (size_t)BUF_ELEMS;
    u16* WtA   = wbase;                 // [768][256]: Wq_i^T, Wk_t^T, Wv_t^T
    u16* WtB   = wbase + 196608;        // [768][256]: Wq_t^T, Wk_i^T, Wv_i^T
    u16* Wt_oi = wbase + 393216;        // [256][256]
    u16* Wt_ot = wbase + 458752;
    u16* Wt_en = wbase + 524288;        // [256][512]
    float* biasA = (float*)(wbase + 655360);  // [768]
    float* biasB = biasA + 768;

    dim3 blk(256);
    // ---- prep: transposed bf16 weights + concat biases ----
    WT wt;
    wt.src[0] = wq_i; wt.dst[0] = WtA;
    wt.src[1] = wk_t; wt.dst[1] = WtA + 65536;
    wt.src[2] = wv_t; wt.dst[2] = WtA + 131072;
    wt.src[3] = wq_t; wt.dst[3] = WtB;
    wt.src[4] = wk_i; wt.dst[4] = WtB + 65536;
    wt.src[5] = wv_i; wt.dst[5] = WtB + 131072;
    wt.src[6] = wo_i; wt.dst[6] = Wt_oi;
    wt.src[7] = wo_t; wt.dst[7] = Wt_ot;
    wt.src[8] = enh_w; wt.dst[8] = Wt_en;
    wt.bs[0] = bq_i; wt.bs[1] = bk_t; wt.bs[2] = bv_t;
    wt.bs[3] = bq_t; wt.bs[4] = bk_i; wt.bs[5] = bv_i;
    wt.bA = biasA; wt.bB = biasB;
    wtrans_kernel<<<161, blk, 0, stream>>>(wt);

    // ---- fused QKV projections (2 dispatches, N=768) ----
    // img @ [Wq_i | Wk_t | Wv_t] -> {B0, B4, B5}
    gemm_mfma<0><<<768, blk, 0, stream>>>(img, nullptr, nullptr, WtA, nullptr,
                                          biasA, nullptr, B0, B4, B5);
    // txt @ [Wq_t | Wk_i | Wv_i] -> {B3, B1, B2}
    gemm_mfma<0><<<768, blk, 0, stream>>>(txt, nullptr, nullptr, WtB, nullptr,
                                          biasB, nullptr, B3, B1, B2);
    // ---- both attentions, output in-place over Q ----
    attn_mfma<<<2048, blk, 0, stream>>>(B0, B1, B2, B0, B3, B4, B5, B3);
    // ---- output projections, M-stacked ----
    gemm_mfma<1><<<512, blk, 0, stream>>>(nullptr, B0, B3, Wt_oi, Wt_ot,
                                          bo_i, bo_t, B1, B4, nullptr);
    // ---- residual + LN, both halves ----
    ln_res_kernel<<<8192, blk, 0, stream>>>(B1, B4, img, txt,
                                            lng_i, lnb_i, lng_t, lnb_t, B2, B5);
    // ---- enhancement (concat-K, fp32 out) + inconsistency ----
    gemm_mfma<2><<<256, blk, 0, stream>>>(nullptr, B2, B5, Wt_en, nullptr,
                                          enh_b, nullptr, out, nullptr, nullptr);
    inc_kernel<<<16, blk, 0, stream>>>(img_sp, txt_sp, incw, incb,
                                       out + 4194304, out + 4198400, out + 4202496);
}

// Round 8
// 311.932 us; speedup vs baseline: 4.5744x; 1.0737x over previous
//
#include <hip/hip_runtime.h>
#include <stdint.h>

typedef unsigned int u32;
typedef unsigned short u16;
typedef __attribute__((ext_vector_type(8))) short bf16x8;
typedef __attribute__((ext_vector_type(4))) float f32x4;

#define BUF_ELEMS (16384 * 256)

__device__ __forceinline__ float bflo(u32 u) { return __uint_as_float(u << 16); }
__device__ __forceinline__ float bfhi(u32 u) { return __uint_as_float(u & 0xffff0000u); }
__device__ __forceinline__ u16 f2bf(float f) {
    u32 u = __float_as_uint(f);
    return (u16)((u + 0x7fffu + ((u >> 16) & 1u)) >> 16);
}
// pack high halves of two f32 -> u32 (truncation-round bf16 pair, lo first)
__device__ __forceinline__ u32 pkhi(float lo, float hi) {
    return __builtin_amdgcn_perm(__float_as_uint(hi), __float_as_uint(lo), 0x07060302u);
}

// ---------------------------------------------------------------------------
// wtrans: 9x W[k][n] fp32 -> Wt[n][k] bf16; block 160 = QKV bias concat;
// blocks 161..176 = inconsistency GEMM + passthroughs (independent work).
// ---------------------------------------------------------------------------
struct WT {
    const float* src[9];
    u16* dst[9];
    const float* bs[6];   // bq_i, bk_t, bv_t, bq_t, bk_i, bv_i
    float* bA;            // [768]
    float* bB;            // [768]
    const float* img_sp;
    const float* txt_sp;
    const float* incw;
    const float* incb;
    float* out_inc;
    float* out_img;
    float* out_txt;
};

__global__ __launch_bounds__(256)
void wtrans_kernel(WT wt)
{
    __shared__ float T[64][65];
    const int bid = blockIdx.x, t = threadIdx.x;
    if (bid == 160) {
        wt.bA[t]       = wt.bs[0][t];
        wt.bA[256 + t] = wt.bs[1][t];
        wt.bA[512 + t] = wt.bs[2][t];
        wt.bB[t]       = wt.bs[3][t];
        wt.bB[256 + t] = wt.bs[4][t];
        wt.bB[512 + t] = wt.bs[5][t];
        return;
    }
    if (bid > 160) {
        float* iv = &T[0][0];
        const int b = bid - 161, n = t;
        float a = wt.img_sp[b * 256 + n];
        float x = wt.txt_sp[b * 256 + n];
        iv[n] = a - x;
        iv[256 + n] = a * x;
        __syncthreads();
        float acc = wt.incb[n];
        for (int k = 0; k < 512; k++) acc += iv[k] * wt.incw[k * 256 + n];
        wt.out_inc[b * 256 + n] = acc;
        wt.out_img[b * 256 + n] = a;
        wt.out_txt[b * 256 + n] = x;
        return;
    }
    int m, sub;
    if (bid < 128) { m = bid >> 4; sub = bid & 15; }
    else           { m = 8;        sub = bid - 128; }
    const int K = (m == 8) ? 512 : 256;
    const int kt = (m == 8) ? (sub & 7) : (sub & 3);
    const int nt = (m == 8) ? (sub >> 3) : (sub >> 2);
    const int k0 = kt * 64, n0 = nt * 64;
    const float* src = wt.src[m];
    u16* dst = wt.dst[m];

    const int kk = t >> 2, nn = (t & 3) * 16;
    #pragma unroll
    for (int j = 0; j < 16; j += 4) {
        float4 v = *(const float4*)(src + (size_t)(k0 + kk) * 256 + n0 + nn + j);
        T[kk][nn + j + 0] = v.x; T[kk][nn + j + 1] = v.y;
        T[kk][nn + j + 2] = v.z; T[kk][nn + j + 3] = v.w;
    }
    __syncthreads();
    const int nn2 = t >> 2, kc = (t & 3) * 16;
    #pragma unroll
    for (int j = 0; j < 16; j++)
        dst[(size_t)(n0 + nn2) * K + k0 + kc + j] = f2bf(T[kc + j][nn2]);
}

// ---------------------------------------------------------------------------
// Unified MFMA GEMM. 128x128 tile, 4 waves (2x2 of 64x64), BK=64.
// MODE 0 QKV : A fp32 (in-register cvt), N=768, K=256; Q group (n0<256)
//              pre-scaled by 1/sqrt(32)*log2(e) for the attention exp2.
// MODE 1 OPRJ: A bf16, M=32768 m-stacked, N=256.
// MODE 2 ENH : A bf16 x2 kt-concat (K=512), N=256, fp32 out.
// ---------------------------------------------------------------------------
template<int MODE>
__global__ __launch_bounds__(256)
void gemm_mfma(const float* __restrict__ Af,
               const u16* __restrict__ Ab0, const u16* __restrict__ Ab1,
               const u16* __restrict__ Wt0, const u16* __restrict__ Wt1,
               const float* __restrict__ bias0, const float* __restrict__ bias1,
               void* __restrict__ o0, void* __restrict__ o1, void* __restrict__ o2)
{
    __shared__ u16 As[128][72];
    __shared__ u16 Bs[128][72];
    const int tid = threadIdx.x;
    const int wave = tid >> 6, lane = tid & 63;
    const int L = lane & 15, Qd = lane >> 4;
    int m0, n0;
    if (MODE == 0) { n0 = (blockIdx.x % 6) * 128; m0 = (blockIdx.x / 6) * 128; }
    else           { n0 = (blockIdx.x & 1) * 128; m0 = (blockIdx.x >> 1) * 128; }
    const bool msel = (MODE == 1) && (m0 >= 16384);
    const int lm0 = msel ? (m0 - 16384) : m0;
    const u16* Wt = (MODE == 1 && msel) ? Wt1 : Wt0;
    const float* bias = (MODE == 1 && msel) ? bias1 : bias0;
    const int wr = wave & 1, wc = wave >> 1;
    const int sr = tid >> 1, sh = (tid & 1) * 32;
    const int KS = (MODE == 2) ? 512 : 256;

    f32x4 acc[4][4] = {};

    for (int kt = 0; kt < KS; kt += 64) {
        // ---- stage A ----
        if (MODE == 0) {
            const float* Ap = Af + (size_t)(m0 + sr) * 256 + kt + sh;
            uint4 pk[2];
            #pragma unroll
            for (int half = 0; half < 2; half++) {
                float4 f0 = *(const float4*)(Ap + half * 16);
                float4 f1 = *(const float4*)(Ap + half * 16 + 4);
                float4 f2 = *(const float4*)(Ap + half * 16 + 8);
                float4 f3 = *(const float4*)(Ap + half * 16 + 12);
                pk[half].x = pkhi(f0.x, f0.y);
                pk[half].y = pkhi(f0.z, f0.w);
                pk[half].z = pkhi(f1.x, f1.y);
                pk[half].w = pkhi(f1.z, f1.w);
                uint4 q;
                q.x = pkhi(f2.x, f2.y); q.y = pkhi(f2.z, f2.w);
                q.z = pkhi(f3.x, f3.y); q.w = pkhi(f3.z, f3.w);
                *(uint4*)&As[sr][sh + half * 16 + 8] = q;
            }
            *(uint4*)&As[sr][sh + 0] = pk[0];
            *(uint4*)&As[sr][sh + 16] = pk[1];
        } else {
            const u16* Abase;
            int lkt = kt;
            if (MODE == 2) { Abase = (kt < 256) ? Ab0 : Ab1; lkt = kt & 255; }
            else           { Abase = msel ? Ab1 : Ab0; }
            const u16* Ap = Abase + (size_t)(lm0 + sr) * 256 + lkt + sh;
            uint4 a0 = *(const uint4*)(Ap + 0);
            uint4 a1 = *(const uint4*)(Ap + 8);
            uint4 a2 = *(const uint4*)(Ap + 16);
            uint4 a3 = *(const uint4*)(Ap + 24);
            *(uint4*)&As[sr][sh + 0]  = a0;
            *(uint4*)&As[sr][sh + 8]  = a1;
            *(uint4*)&As[sr][sh + 16] = a2;
            *(uint4*)&As[sr][sh + 24] = a3;
        }
        // ---- stage B (Wt is n-major [n][k], stride KS) ----
        {
            const u16* Bp = Wt + (size_t)(n0 + sr) * KS + kt + sh;
            uint4 w0 = *(const uint4*)(Bp + 0);
            uint4 w1 = *(const uint4*)(Bp + 8);
            uint4 w2 = *(const uint4*)(Bp + 16);
            uint4 w3 = *(const uint4*)(Bp + 24);
            *(uint4*)&Bs[sr][sh + 0]  = w0;
            *(uint4*)&Bs[sr][sh + 8]  = w1;
            *(uint4*)&Bs[sr][sh + 16] = w2;
            *(uint4*)&Bs[sr][sh + 24] = w3;
        }
        __syncthreads();
        #pragma unroll
        for (int kh = 0; kh < 64; kh += 32) {
            bf16x8 af[4], bf[4];
            #pragma unroll
            for (int mt = 0; mt < 4; mt++)
                af[mt] = *(const bf16x8*)&As[wr * 64 + mt * 16 + L][kh + Qd * 8];
            #pragma unroll
            for (int nt = 0; nt < 4; nt++)
                bf[nt] = *(const bf16x8*)&Bs[wc * 64 + nt * 16 + L][kh + Qd * 8];
            #pragma unroll
            for (int mt = 0; mt < 4; mt++)
                #pragma unroll
                for (int nt = 0; nt < 4; nt++)
                    acc[mt][nt] = __builtin_amdgcn_mfma_f32_16x16x32_bf16(
                        af[mt], bf[nt], acc[mt][nt], 0, 0, 0);
        }
        __syncthreads();
    }

    // ---- epilogue ----
    float bvals[4];
    #pragma unroll
    for (int nt = 0; nt < 4; nt++)
        bvals[nt] = bias[n0 + wc * 64 + nt * 16 + L];

    // Q outputs (MODE 0, n-group 0) carry the softmax scale * log2(e)
    const float qsc = (MODE == 0 && n0 < 256)
                      ? (0.17677669529663687f * 1.4426950408889634f) : 1.0f;

    void* outp;
    int colb;
    if (MODE == 0) {
        const int g = n0 >> 8;
        outp = (g == 0) ? o0 : ((g == 1) ? o1 : o2);
        colb = (n0 & 255) + wc * 64;
    } else if (MODE == 1) {
        outp = msel ? o1 : o0;
        colb = n0 + wc * 64;
    } else {
        outp = o0;
        colb = n0 + wc * 64;
    }
    #pragma unroll
    for (int mt = 0; mt < 4; mt++) {
        #pragma unroll
        for (int r = 0; r < 4; r++) {
            const size_t row = (size_t)(lm0 + wr * 64 + mt * 16 + Qd * 4 + r) * 256;
            #pragma unroll
            for (int nt = 0; nt < 4; nt++) {
                const int col = colb + nt * 16 + L;
                float v = (acc[mt][nt][r] + bvals[nt]) * qsc;
                if (MODE == 2) ((float*)outp)[row + col] = v;
                else           ((u16*)outp)[row + col] = f2bf(v);
            }
        }
    }
}

// ---------------------------------------------------------------------------
// MFMA flash attention, both sets in one dispatch. 128 q-rows/block (2 sub-
// tiles of 64), K-tile 128 keys. Virtual key order v=(key&15)*8+(key>>4).
// Ps is per-wave private -> reused across the 2 q-subtiles (4 tiles, not 8):
// LDS 36.4KB -> 4 blocks/CU. Row-sums via ones-B MFMA (no VALU adds).
// Q is pre-scaled by 1/sqrt(32)*log2e -> bare exp2f here.
// grid 2048 = 2 sets * 16 b * 8 h * 8 qt; block 256.
// ---------------------------------------------------------------------------
__global__ __launch_bounds__(256, 4)
void attn_mfma(const u16* __restrict__ Q0, const u16* __restrict__ K0,
               const u16* __restrict__ V0, u16* __restrict__ O0,
               const u16* __restrict__ Q1, const u16* __restrict__ K1,
               const u16* __restrict__ V1, u16* __restrict__ O1)
{
    __shared__ u16 Ks[128][40];      // [key][dim]
    __shared__ u16 Vt[32][136];      // [dim][v-key]
    __shared__ u16 Ps[4][16][136];   // [wave][q][v-key], reused across qs
    const int tid = threadIdx.x;
    const int wave = tid >> 6, lane = tid & 63;
    const int L = lane & 15, Qd = lane >> 4;
    const int bid = blockIdx.x;
    const int set = bid >> 10;
    const int r3 = bid & 1023;
    const int qt = r3 & 7;
    const int h = (r3 >> 3) & 7;
    const int b = r3 >> 6;
    const u16* Q = set ? Q1 : Q0;
    const u16* K = set ? K1 : K0;
    const u16* V = set ? V1 : V0;
    u16* O = set ? O1 : O0;
    const int rowbase = b * 1024;
    const int qbase = rowbase + qt * 128;

    bf16x8 qfrag[2];
    #pragma unroll
    for (int qs = 0; qs < 2; qs++)
        qfrag[qs] = *(const bf16x8*)(Q + (size_t)(qbase + qs * 64 + wave * 16 + L) * 256
                                       + h * 32 + Qd * 8);

    const short oneb = (short)0x3F80;
    const bf16x8 ones = {oneb, oneb, oneb, oneb, oneb, oneb, oneb, oneb};

    f32x4 oacc[2][2] = {};
    f32x4 oaccL[2] = {};

    const int sr = tid >> 1;          // key 0..127
    const int scol = (tid & 1) * 16;  // dim half
    const int vcol = (sr & 15) * 8 + (sr >> 4);

    for (int t = 0; t < 8; t++) {
        const size_t kvbase = (size_t)(rowbase + t * 128 + sr) * 256 + h * 32 + scol;
        uint4 k1 = *(const uint4*)(K + kvbase);
        uint4 k2 = *(const uint4*)(K + kvbase + 8);
        uint4 v1 = *(const uint4*)(V + kvbase);
        uint4 v2 = *(const uint4*)(V + kvbase + 8);
        *(uint4*)&Ks[sr][scol]     = k1;
        *(uint4*)&Ks[sr][scol + 8] = k2;
        union { uint4 u4[2]; u16 us[16]; } vv;
        vv.u4[0] = v1; vv.u4[1] = v2;
        #pragma unroll
        for (int j = 0; j < 16; j++) Vt[scol + j][vcol] = vv.us[j];
        __syncthreads();

        #pragma unroll
        for (int qs = 0; qs < 2; qs++) {
            const f32x4 z = {0.f, 0.f, 0.f, 0.f};
            f32x4 sacc[8];
            #pragma unroll
            for (int ct = 0; ct < 8; ct++) {
                bf16x8 kfrag = *(const bf16x8*)&Ks[ct * 16 + L][Qd * 8];
                sacc[ct] = __builtin_amdgcn_mfma_f32_16x16x32_bf16(qfrag[qs], kfrag, z, 0, 0, 0);
            }
            #pragma unroll
            for (int r = 0; r < 4; r++) {
                float p[8];
                #pragma unroll
                for (int ct = 0; ct < 8; ct++) p[ct] = exp2f(sacc[ct][r]);
                uint4 pk;
                pk.x = pkhi(p[0], p[1]);
                pk.y = pkhi(p[2], p[3]);
                pk.z = pkhi(p[4], p[5]);
                pk.w = pkhi(p[6], p[7]);
                *(uint4*)&Ps[wave][Qd * 4 + r][L * 8] = pk;
            }
            #pragma unroll
            for (int kc = 0; kc < 4; kc++) {
                bf16x8 pfrag = *(const bf16x8*)&Ps[wave][L][kc * 32 + Qd * 8];
                bf16x8 vf0 = *(const bf16x8*)&Vt[L][kc * 32 + Qd * 8];
                bf16x8 vf1 = *(const bf16x8*)&Vt[16 + L][kc * 32 + Qd * 8];
                oacc[qs][0] = __builtin_amdgcn_mfma_f32_16x16x32_bf16(pfrag, vf0, oacc[qs][0], 0, 0, 0);
                oacc[qs][1] = __builtin_amdgcn_mfma_f32_16x16x32_bf16(pfrag, vf1, oacc[qs][1], 0, 0, 0);
                oaccL[qs]   = __builtin_amdgcn_mfma_f32_16x16x32_bf16(pfrag, ones, oaccL[qs], 0, 0, 0);
            }
        }
        __syncthreads();
    }

    #pragma unroll
    for (int qs = 0; qs < 2; qs++) {
        #pragma unroll
        for (int r = 0; r < 4; r++) {
            float inv = 1.f / oaccL[qs][r];
            const size_t orow = (size_t)(qbase + qs * 64 + wave * 16 + Qd * 4 + r) * 256 + h * 32;
            O[orow + L]      = f2bf(oacc[qs][0][r] * inv);
            O[orow + 16 + L] = f2bf(oacc[qs][1][r] * inv);
        }
    }
}

// ---------------------------------------------------------------------------
// Residual + LayerNorm, both halves in one dispatch.
// ---------------------------------------------------------------------------
__global__ __launch_bounds__(256)
void ln_res_kernel(const u16* __restrict__ P0, const u16* __restrict__ P1,
                   const float* __restrict__ R0, const float* __restrict__ R1,
                   const float* __restrict__ g0, const float* __restrict__ be0,
                   const float* __restrict__ g1, const float* __restrict__ be1,
                   u16* __restrict__ out0, u16* __restrict__ out1)
{
    const int lane = threadIdx.x & 63;
    int row = blockIdx.x * 4 + (threadIdx.x >> 6);
    const bool sel = row >= 16384;
    const u16* P = sel ? P1 : P0;
    const float* R = sel ? R1 : R0;
    const float* g = sel ? g1 : g0;
    const float* be = sel ? be1 : be0;
    u16* out = sel ? out1 : out0;
    if (sel) row -= 16384;
    const int col = lane * 4;
    uint2 pv = *(const uint2*)(P + (size_t)row * 256 + col);
    float4 rv = *(const float4*)(R + (size_t)row * 256 + col);
    float x0 = bflo(pv.x) + rv.x;
    float x1 = bfhi(pv.x) + rv.y;
    float x2 = bflo(pv.y) + rv.z;
    float x3 = bfhi(pv.y) + rv.w;
    float s = x0 + x1 + x2 + x3;
    float s2 = x0*x0 + x1*x1 + x2*x2 + x3*x3;
    #pragma unroll
    for (int off = 32; off > 0; off >>= 1) {
        s  += __shfl_xor(s, off);
        s2 += __shfl_xor(s2, off);
    }
    float mean = s * 0.00390625f;
    float var = fmaxf(s2 * 0.00390625f - mean * mean, 0.f);
    float rstd = rsqrtf(var + 1e-5f);
    float4 gv = *(const float4*)(g + col);
    float4 bv = *(const float4*)(be + col);
    uint2 pk;
    pk.x = (u32)f2bf((x0 - mean) * rstd * gv.x + bv.x)
         | ((u32)f2bf((x1 - mean) * rstd * gv.y + bv.y) << 16);
    pk.y = (u32)f2bf((x2 - mean) * rstd * gv.z + bv.z)
         | ((u32)f2bf((x3 - mean) * rstd * gv.w + bv.w) << 16);
    *(uint2*)(out + (size_t)row * 256 + col) = pk;
}

// ---------------------------------------------------------------------------
extern "C" void kernel_launch(void* const* d_in, const int* in_sizes, int n_in,
                              void* d_out, int out_size, void* d_ws, size_t ws_size,
                              hipStream_t stream)
{
    (void)in_sizes; (void)n_in; (void)out_size; (void)ws_size;
    const float* img    = (const float*)d_in[0];
    const float* txt    = (const float*)d_in[1];
    const float* img_sp = (const float*)d_in[2];
    const float* txt_sp = (const float*)d_in[3];
    const float* wq_i = (const float*)d_in[4];  const float* bq_i = (const float*)d_in[5];
    const float* wk_i = (const float*)d_in[6];  const float* bk_i = (const float*)d_in[7];
    const float* wv_i = (const float*)d_in[8];  const float* bv_i = (const float*)d_in[9];
    const float* wo_i = (const float*)d_in[10]; const float* bo_i = (const float*)d_in[11];
    const float* wq_t = (const float*)d_in[12]; const float* bq_t = (const float*)d_in[13];
    const float* wk_t = (const float*)d_in[14]; const float* bk_t = (const float*)d_in[15];
    const float* wv_t = (const float*)d_in[16]; const float* bv_t = (const float*)d_in[17];
    const float* wo_t = (const float*)d_in[18]; const float* bo_t = (const float*)d_in[19];
    const float* lng_i = (const float*)d_in[20]; const float* lnb_i = (const float*)d_in[21];
    const float* lng_t = (const float*)d_in[22]; const float* lnb_t = (const float*)d_in[23];
    const float* enh_w = (const float*)d_in[24]; const float* enh_b = (const float*)d_in[25];
    const float* incw  = (const float*)d_in[26]; const float* incb  = (const float*)d_in[27];
    float* out = (float*)d_out;
    u16* wsp = (u16*)d_ws;
    u16* B0 = wsp;
    u16* B1 = wsp + 1 * (size_t)BUF_ELEMS;
    u16* B2 = wsp + 2 * (size_t)BUF_ELEMS;
    u16* B3 = wsp + 3 * (size_t)BUF_ELEMS;
    u16* B4 = wsp + 4 * (size_t)BUF_ELEMS;
    u16* B5 = wsp + 5 * (size_t)BUF_ELEMS;
    u16* wbase = wsp + 6 * (size_t)BUF_ELEMS;
    u16* WtA   = wbase;                 // [768][256]: Wq_i^T, Wk_t^T, Wv_t^T
    u16* WtB   = wbase + 196608;        // [768][256]: Wq_t^T, Wk_i^T, Wv_i^T
    u16* Wt_oi = wbase + 393216;
    u16* Wt_ot = wbase + 458752;
    u16* Wt_en = wbase + 524288;        // [256][512]
    float* biasA = (float*)(wbase + 655360);  // [768]
    float* biasB = biasA + 768;

    dim3 blk(256);
    // ---- prep: weights + biases + inconsistency/passthrough ----
    WT wt;
    wt.src[0] = wq_i; wt.dst[0] = WtA;
    wt.src[1] = wk_t; wt.dst[1] = WtA + 65536;
    wt.src[2] = wv_t; wt.dst[2] = WtA + 131072;
    wt.src[3] = wq_t; wt.dst[3] = WtB;
    wt.src[4] = wk_i; wt.dst[4] = WtB + 65536;
    wt.src[5] = wv_i; wt.dst[5] = WtB + 131072;
    wt.src[6] = wo_i; wt.dst[6] = Wt_oi;
    wt.src[7] = wo_t; wt.dst[7] = Wt_ot;
    wt.src[8] = enh_w; wt.dst[8] = Wt_en;
    wt.bs[0] = bq_i; wt.bs[1] = bk_t; wt.bs[2] = bv_t;
    wt.bs[3] = bq_t; wt.bs[4] = bk_i; wt.bs[5] = bv_i;
    wt.bA = biasA; wt.bB = biasB;
    wt.img_sp = img_sp; wt.txt_sp = txt_sp; wt.incw = incw; wt.incb = incb;
    wt.out_inc = out + 4194304; wt.out_img = out + 4198400; wt.out_txt = out + 4202496;
    wtrans_kernel<<<177, blk, 0, stream>>>(wt);

    // ---- fused QKV projections (Q group pre-scaled) ----
    gemm_mfma<0><<<768, blk, 0, stream>>>(img, nullptr, nullptr, WtA, nullptr,
                                          biasA, nullptr, B0, B4, B5);
    gemm_mfma<0><<<768, blk, 0, stream>>>(txt, nullptr, nullptr, WtB, nullptr,
                                          biasB, nullptr, B3, B1, B2);
    // ---- both attentions, output in-place over Q ----
    attn_mfma<<<2048, blk, 0, stream>>>(B0, B1, B2, B0, B3, B4, B5, B3);
    // ---- output projections, M-stacked ----
    gemm_mfma<1><<<512, blk, 0, stream>>>(nullptr, B0, B3, Wt_oi, Wt_ot,
                                          bo_i, bo_t, B1, B4, nullptr);
    // ---- residual + LN, both halves ----
    ln_res_kernel<<<8192, blk, 0, stream>>>(B1, B4, img, txt,
                                            lng_i, lnb_i, lng_t, lnb_t, B2, B5);
    // ---- enhancement (concat-K, fp32 out) ----
    gemm_mfma<2><<<256, blk, 0, stream>>>(nullptr, B2, B5, Wt_en, nullptr,
                                          enh_b, nullptr, out, nullptr, nullptr);
}

// Round 9
// 309.752 us; speedup vs baseline: 4.6065x; 1.0070x over previous
//
#include <hip/hip_runtime.h>
#include <stdint.h>

typedef unsigned int u32;
typedef unsigned short u16;
typedef __attribute__((ext_vector_type(8))) short bf16x8;
typedef __attribute__((ext_vector_type(4))) float f32x4;

#define BUF_ELEMS (16384 * 256)

__device__ __forceinline__ float bflo(u32 u) { return __uint_as_float(u << 16); }
__device__ __forceinline__ float bfhi(u32 u) { return __uint_as_float(u & 0xffff0000u); }
__device__ __forceinline__ u16 f2bf(float f) {
    u32 u = __float_as_uint(f);
    return (u16)((u + 0x7fffu + ((u >> 16) & 1u)) >> 16);
}
// pack high halves of two f32 -> u32 (truncation-round bf16 pair, lo first)
__device__ __forceinline__ u32 pkhi(float lo, float hi) {
    return __builtin_amdgcn_perm(__float_as_uint(hi), __float_as_uint(lo), 0x07060302u);
}

// ---------------------------------------------------------------------------
// wtrans: 9x W[k][n] fp32 -> Wt[n][k] bf16; block 160 = QKV bias concat;
// blocks 161..176 = inconsistency GEMM + passthroughs (independent work).
// ---------------------------------------------------------------------------
struct WT {
    const float* src[9];
    u16* dst[9];
    const float* bs[6];   // bq_i, bk_t, bv_t, bq_t, bk_i, bv_i
    float* bA;            // [768]
    float* bB;            // [768]
    const float* img_sp;
    const float* txt_sp;
    const float* incw;
    const float* incb;
    float* out_inc;
    float* out_img;
    float* out_txt;
};

__global__ __launch_bounds__(256)
void wtrans_kernel(WT wt)
{
    __shared__ float T[64][65];
    const int bid = blockIdx.x, t = threadIdx.x;
    if (bid == 160) {
        wt.bA[t]       = wt.bs[0][t];
        wt.bA[256 + t] = wt.bs[1][t];
        wt.bA[512 + t] = wt.bs[2][t];
        wt.bB[t]       = wt.bs[3][t];
        wt.bB[256 + t] = wt.bs[4][t];
        wt.bB[512 + t] = wt.bs[5][t];
        return;
    }
    if (bid > 160) {
        float* iv = &T[0][0];
        const int b = bid - 161, n = t;
        float a = wt.img_sp[b * 256 + n];
        float x = wt.txt_sp[b * 256 + n];
        iv[n] = a - x;
        iv[256 + n] = a * x;
        __syncthreads();
        float acc = wt.incb[n];
        for (int k = 0; k < 512; k++) acc += iv[k] * wt.incw[k * 256 + n];
        wt.out_inc[b * 256 + n] = acc;
        wt.out_img[b * 256 + n] = a;
        wt.out_txt[b * 256 + n] = x;
        return;
    }
    int m, sub;
    if (bid < 128) { m = bid >> 4; sub = bid & 15; }
    else           { m = 8;        sub = bid - 128; }
    const int K = (m == 8) ? 512 : 256;
    const int kt = (m == 8) ? (sub & 7) : (sub & 3);
    const int nt = (m == 8) ? (sub >> 3) : (sub >> 2);
    const int k0 = kt * 64, n0 = nt * 64;
    const float* src = wt.src[m];
    u16* dst = wt.dst[m];

    const int kk = t >> 2, nn = (t & 3) * 16;
    #pragma unroll
    for (int j = 0; j < 16; j += 4) {
        float4 v = *(const float4*)(src + (size_t)(k0 + kk) * 256 + n0 + nn + j);
        T[kk][nn + j + 0] = v.x; T[kk][nn + j + 1] = v.y;
        T[kk][nn + j + 2] = v.z; T[kk][nn + j + 3] = v.w;
    }
    __syncthreads();
    const int nn2 = t >> 2, kc = (t & 3) * 16;
    #pragma unroll
    for (int j = 0; j < 16; j++)
        dst[(size_t)(n0 + nn2) * K + k0 + kc + j] = f2bf(T[kc + j][nn2]);
}

// ---------------------------------------------------------------------------
// Unified MFMA GEMM. 128x128 tile, 4 waves (2x2 of 64x64), BK=64.
// All modes: bid = n_idx * (#m-blocks) + m_idx so tiles sharing the same A
// row-block are congruent mod 8 -> same XCD -> A served from L2.
// MODE 0 QKV : A fp32 img/txt m-stacked (in-register cvt), N=768, K=256.
//              Q n-group (n_idx<2) pre-scaled by 1/sqrt(32)*log2(e).
//              grid 1536 = 6 n * 256 m.
// MODE 1 OPRJ: A bf16, M=32768 m-stacked, N=256. grid 512 = 2 n * 256 m.
// MODE 2 ENH : A bf16 x2 kt-concat (K=512), N=256, fp32 out. grid 256.
// ---------------------------------------------------------------------------
template<int MODE>
__global__ __launch_bounds__(256)
void gemm_mfma(const float* __restrict__ Af0, const float* __restrict__ Af1,
               const u16* __restrict__ Ab0, const u16* __restrict__ Ab1,
               const u16* __restrict__ Wt0, const u16* __restrict__ Wt1,
               const float* __restrict__ bias0, const float* __restrict__ bias1,
               void* __restrict__ o0, void* __restrict__ o1, void* __restrict__ o2,
               void* __restrict__ o3, void* __restrict__ o4, void* __restrict__ o5)
{
    __shared__ u16 As[128][72];
    __shared__ u16 Bs[128][72];
    const int tid = threadIdx.x;
    const int wave = tid >> 6, lane = tid & 63;
    const int L = lane & 15, Qd = lane >> 4;
    int m_idx, n_idx;
    if (MODE == 0)      { m_idx = blockIdx.x & 255; n_idx = blockIdx.x >> 8; }
    else if (MODE == 1) { m_idx = blockIdx.x & 255; n_idx = blockIdx.x >> 8; }
    else                { m_idx = blockIdx.x & 127; n_idx = blockIdx.x >> 7; }
    const bool msel = (MODE != 2) && (m_idx >= 128 * (MODE == 0 ? 1 : 1) && MODE == 0
                       ? (m_idx >= 128) : (MODE == 1 && m_idx >= 128));
    // (simplified below)
    const bool ms = (MODE == 0 || MODE == 1) ? (m_idx >= 128) : false;
    const int lm0 = (MODE == 2) ? m_idx * 128 : (m_idx & 127) * 128;
    const int n0 = n_idx * 128;
    const u16* Wt = ms ? Wt1 : Wt0;
    const float* bias = ms ? bias1 : bias0;
    const int wr = wave & 1, wc = wave >> 1;
    const int sr = tid >> 1, sh = (tid & 1) * 32;
    const int KS = (MODE == 2) ? 512 : 256;
    (void)msel;

    f32x4 acc[4][4] = {};

    for (int kt = 0; kt < KS; kt += 64) {
        // ---- stage A ----
        if (MODE == 0) {
            const float* Af = ms ? Af1 : Af0;
            const float* Ap = Af + (size_t)(lm0 + sr) * 256 + kt + sh;
            uint4 pk[2];
            #pragma unroll
            for (int half = 0; half < 2; half++) {
                float4 f0 = *(const float4*)(Ap + half * 16);
                float4 f1 = *(const float4*)(Ap + half * 16 + 4);
                float4 f2 = *(const float4*)(Ap + half * 16 + 8);
                float4 f3 = *(const float4*)(Ap + half * 16 + 12);
                pk[half].x = pkhi(f0.x, f0.y);
                pk[half].y = pkhi(f0.z, f0.w);
                pk[half].z = pkhi(f1.x, f1.y);
                pk[half].w = pkhi(f1.z, f1.w);
                uint4 q;
                q.x = pkhi(f2.x, f2.y); q.y = pkhi(f2.z, f2.w);
                q.z = pkhi(f3.x, f3.y); q.w = pkhi(f3.z, f3.w);
                *(uint4*)&As[sr][sh + half * 16 + 8] = q;
            }
            *(uint4*)&As[sr][sh + 0] = pk[0];
            *(uint4*)&As[sr][sh + 16] = pk[1];
        } else {
            const u16* Abase;
            int lkt = kt;
            if (MODE == 2) { Abase = (kt < 256) ? Ab0 : Ab1; lkt = kt & 255; }
            else           { Abase = ms ? Ab1 : Ab0; }
            const u16* Ap = Abase + (size_t)(lm0 + sr) * 256 + lkt + sh;
            uint4 a0 = *(const uint4*)(Ap + 0);
            uint4 a1 = *(const uint4*)(Ap + 8);
            uint4 a2 = *(const uint4*)(Ap + 16);
            uint4 a3 = *(const uint4*)(Ap + 24);
            *(uint4*)&As[sr][sh + 0]  = a0;
            *(uint4*)&As[sr][sh + 8]  = a1;
            *(uint4*)&As[sr][sh + 16] = a2;
            *(uint4*)&As[sr][sh + 24] = a3;
        }
        // ---- stage B (Wt is n-major [n][k], stride KS) ----
        {
            const u16* Bp = Wt + (size_t)(n0 + sr) * KS + kt + sh;
            uint4 w0 = *(const uint4*)(Bp + 0);
            uint4 w1 = *(const uint4*)(Bp + 8);
            uint4 w2 = *(const uint4*)(Bp + 16);
            uint4 w3 = *(const uint4*)(Bp + 24);
            *(uint4*)&Bs[sr][sh + 0]  = w0;
            *(uint4*)&Bs[sr][sh + 8]  = w1;
            *(uint4*)&Bs[sr][sh + 16] = w2;
            *(uint4*)&Bs[sr][sh + 24] = w3;
        }
        __syncthreads();
        #pragma unroll
        for (int kh = 0; kh < 64; kh += 32) {
            bf16x8 af[4], bf[4];
            #pragma unroll
            for (int mt = 0; mt < 4; mt++)
                af[mt] = *(const bf16x8*)&As[wr * 64 + mt * 16 + L][kh + Qd * 8];
            #pragma unroll
            for (int nt = 0; nt < 4; nt++)
                bf[nt] = *(const bf16x8*)&Bs[wc * 64 + nt * 16 + L][kh + Qd * 8];
            #pragma unroll
            for (int mt = 0; mt < 4; mt++)
                #pragma unroll
                for (int nt = 0; nt < 4; nt++)
                    acc[mt][nt] = __builtin_amdgcn_mfma_f32_16x16x32_bf16(
                        af[mt], bf[nt], acc[mt][nt], 0, 0, 0);
        }
        __syncthreads();
    }

    // ---- epilogue ----
    float bvals[4];
    #pragma unroll
    for (int nt = 0; nt < 4; nt++)
        bvals[nt] = bias[n0 + wc * 64 + nt * 16 + L];

    const float qsc = (MODE == 0 && n_idx < 2)
                      ? (0.17677669529663687f * 1.4426950408889634f) : 1.0f;

    void* outp;
    int colb;
    if (MODE == 0) {
        const int g = n_idx >> 1;
        if (!ms) outp = (g == 0) ? o0 : ((g == 1) ? o1 : o2);
        else     outp = (g == 0) ? o3 : ((g == 1) ? o4 : o5);
        colb = (n_idx & 1) * 128 + wc * 64;
    } else if (MODE == 1) {
        outp = ms ? o1 : o0;
        colb = n0 + wc * 64;
    } else {
        outp = o0;
        colb = n0 + wc * 64;
    }
    #pragma unroll
    for (int mt = 0; mt < 4; mt++) {
        #pragma unroll
        for (int r = 0; r < 4; r++) {
            const size_t row = (size_t)(lm0 + wr * 64 + mt * 16 + Qd * 4 + r) * 256;
            #pragma unroll
            for (int nt = 0; nt < 4; nt++) {
                const int col = colb + nt * 16 + L;
                float v = (acc[mt][nt][r] + bvals[nt]) * qsc;
                if (MODE == 2) ((float*)outp)[row + col] = v;
                else           ((u16*)outp)[row + col] = f2bf(v);
            }
        }
    }
}

// ---------------------------------------------------------------------------
// MFMA flash attention, both sets in one dispatch. 128 q-rows/block, K-tile
// 128 keys. bid = qt*256 + (set,b,h): the 8 qt-sharers of one (b,h) are
// congruent mod 8 -> same XCD -> K/V tiles served from that XCD's L2.
// kfrag (qs-invariant) hoisted to registers (saves 8 b128 LDS reads/t-iter).
// Virtual key order v=(key&15)*8+(key>>4); row-sums via ones-B MFMA;
// Q pre-scaled -> bare exp2f. Output in-place over Q.
// grid 2048; block 256.
// ---------------------------------------------------------------------------
__global__ __launch_bounds__(256, 4)
void attn_mfma(const u16* __restrict__ Q0, const u16* __restrict__ K0,
               const u16* __restrict__ V0, u16* __restrict__ O0,
               const u16* __restrict__ Q1, const u16* __restrict__ K1,
               const u16* __restrict__ V1, u16* __restrict__ O1)
{
    __shared__ u16 Ks[128][40];      // [key][dim]
    __shared__ u16 Vt[32][136];      // [dim][v-key]
    __shared__ u16 Ps[4][16][136];   // [wave][q][v-key], reused across qs
    const int tid = threadIdx.x;
    const int wave = tid >> 6, lane = tid & 63;
    const int L = lane & 15, Qd = lane >> 4;
    const int bid = blockIdx.x;
    const int qt = bid >> 8;         // 0..7 (slow -> XCD-local K/V sharing)
    const int kv = bid & 255;
    const int set = kv >> 7;
    const int b = (kv >> 3) & 15;
    const int h = kv & 7;
    const u16* Q = set ? Q1 : Q0;
    const u16* K = set ? K1 : K0;
    const u16* V = set ? V1 : V0;
    u16* O = set ? O1 : O0;
    const int rowbase = b * 1024;
    const int qbase = rowbase + qt * 128;

    bf16x8 qfrag[2];
    #pragma unroll
    for (int qs = 0; qs < 2; qs++)
        qfrag[qs] = *(const bf16x8*)(Q + (size_t)(qbase + qs * 64 + wave * 16 + L) * 256
                                       + h * 32 + Qd * 8);

    const short oneb = (short)0x3F80;
    const bf16x8 ones = {oneb, oneb, oneb, oneb, oneb, oneb, oneb, oneb};

    f32x4 oacc[2][2] = {};
    f32x4 oaccL[2] = {};

    const int sr = tid >> 1;          // key 0..127
    const int scol = (tid & 1) * 16;  // dim half
    const int vcol = (sr & 15) * 8 + (sr >> 4);

    for (int t = 0; t < 8; t++) {
        const size_t kvbase = (size_t)(rowbase + t * 128 + sr) * 256 + h * 32 + scol;
        uint4 k1 = *(const uint4*)(K + kvbase);
        uint4 k2 = *(const uint4*)(K + kvbase + 8);
        uint4 v1 = *(const uint4*)(V + kvbase);
        uint4 v2 = *(const uint4*)(V + kvbase + 8);
        *(uint4*)&Ks[sr][scol]     = k1;
        *(uint4*)&Ks[sr][scol + 8] = k2;
        union { uint4 u4[2]; u16 us[16]; } vv;
        vv.u4[0] = v1; vv.u4[1] = v2;
        #pragma unroll
        for (int j = 0; j < 16; j++) Vt[scol + j][vcol] = vv.us[j];
        __syncthreads();

        // hoisted K fragments (qs-invariant)
        bf16x8 kf[8];
        #pragma unroll
        for (int ct = 0; ct < 8; ct++)
            kf[ct] = *(const bf16x8*)&Ks[ct * 16 + L][Qd * 8];

        #pragma unroll
        for (int qs = 0; qs < 2; qs++) {
            const f32x4 z = {0.f, 0.f, 0.f, 0.f};
            f32x4 sacc[8];
            #pragma unroll
            for (int ct = 0; ct < 8; ct++)
                sacc[ct] = __builtin_amdgcn_mfma_f32_16x16x32_bf16(qfrag[qs], kf[ct], z, 0, 0, 0);
            #pragma unroll
            for (int r = 0; r < 4; r++) {
                float p[8];
                #pragma unroll
                for (int ct = 0; ct < 8; ct++) p[ct] = exp2f(sacc[ct][r]);
                uint4 pk;
                pk.x = pkhi(p[0], p[1]);
                pk.y = pkhi(p[2], p[3]);
                pk.z = pkhi(p[4], p[5]);
                pk.w = pkhi(p[6], p[7]);
                *(uint4*)&Ps[wave][Qd * 4 + r][L * 8] = pk;
            }
            #pragma unroll
            for (int kc = 0; kc < 4; kc++) {
                bf16x8 pfrag = *(const bf16x8*)&Ps[wave][L][kc * 32 + Qd * 8];
                bf16x8 vf0 = *(const bf16x8*)&Vt[L][kc * 32 + Qd * 8];
                bf16x8 vf1 = *(const bf16x8*)&Vt[16 + L][kc * 32 + Qd * 8];
                oacc[qs][0] = __builtin_amdgcn_mfma_f32_16x16x32_bf16(pfrag, vf0, oacc[qs][0], 0, 0, 0);
                oacc[qs][1] = __builtin_amdgcn_mfma_f32_16x16x32_bf16(pfrag, vf1, oacc[qs][1], 0, 0, 0);
                oaccL[qs]   = __builtin_amdgcn_mfma_f32_16x16x32_bf16(pfrag, ones, oaccL[qs], 0, 0, 0);
            }
        }
        __syncthreads();
    }

    #pragma unroll
    for (int qs = 0; qs < 2; qs++) {
        #pragma unroll
        for (int r = 0; r < 4; r++) {
            float inv = 1.f / oaccL[qs][r];
            const size_t orow = (size_t)(qbase + qs * 64 + wave * 16 + Qd * 4 + r) * 256 + h * 32;
            O[orow + L]      = f2bf(oacc[qs][0][r] * inv);
            O[orow + 16 + L] = f2bf(oacc[qs][1][r] * inv);
        }
    }
}

// ---------------------------------------------------------------------------
// Residual + LayerNorm, both halves in one dispatch.
// ---------------------------------------------------------------------------
__global__ __launch_bounds__(256)
void ln_res_kernel(const u16* __restrict__ P0, const u16* __restrict__ P1,
                   const float* __restrict__ R0, const float* __restrict__ R1,
                   const float* __restrict__ g0, const float* __restrict__ be0,
                   const float* __restrict__ g1, const float* __restrict__ be1,
                   u16* __restrict__ out0, u16* __restrict__ out1)
{
    const int lane = threadIdx.x & 63;
    int row = blockIdx.x * 4 + (threadIdx.x >> 6);
    const bool sel = row >= 16384;
    const u16* P = sel ? P1 : P0;
    const float* R = sel ? R1 : R0;
    const float* g = sel ? g1 : g0;
    const float* be = sel ? be1 : be0;
    u16* out = sel ? out1 : out0;
    if (sel) row -= 16384;
    const int col = lane * 4;
    uint2 pv = *(const uint2*)(P + (size_t)row * 256 + col);
    float4 rv = *(const float4*)(R + (size_t)row * 256 + col);
    float x0 = bflo(pv.x) + rv.x;
    float x1 = bfhi(pv.x) + rv.y;
    float x2 = bflo(pv.y) + rv.z;
    float x3 = bfhi(pv.y) + rv.w;
    float s = x0 + x1 + x2 + x3;
    float s2 = x0*x0 + x1*x1 + x2*x2 + x3*x3;
    #pragma unroll
    for (int off = 32; off > 0; off >>= 1) {
        s  += __shfl_xor(s, off);
        s2 += __shfl_xor(s2, off);
    }
    float mean = s * 0.00390625f;
    float var = fmaxf(s2 * 0.00390625f - mean * mean, 0.f);
    float rstd = rsqrtf(var + 1e-5f);
    float4 gv = *(const float4*)(g + col);
    float4 bv = *(const float4*)(be + col);
    uint2 pk;
    pk.x = (u32)f2bf((x0 - mean) * rstd * gv.x + bv.x)
         | ((u32)f2bf((x1 - mean) * rstd * gv.y + bv.y) << 16);
    pk.y = (u32)f2bf((x2 - mean) * rstd * gv.z + bv.z)
         | ((u32)f2bf((x3 - mean) * rstd * gv.w + bv.w) << 16);
    *(uint2*)(out + (size_t)row * 256 + col) = pk;
}

// ---------------------------------------------------------------------------
extern "C" void kernel_launch(void* const* d_in, const int* in_sizes, int n_in,
                              void* d_out, int out_size, void* d_ws, size_t ws_size,
                              hipStream_t stream)
{
    (void)in_sizes; (void)n_in; (void)out_size; (void)ws_size;
    const float* img    = (const float*)d_in[0];
    const float* txt    = (const float*)d_in[1];
    const float* img_sp = (const float*)d_in[2];
    const float* txt_sp = (const float*)d_in[3];
    const float* wq_i = (const float*)d_in[4];  const float* bq_i = (const float*)d_in[5];
    const float* wk_i = (const float*)d_in[6];  const float* bk_i = (const float*)d_in[7];
    const float* wv_i = (const float*)d_in[8];  const float* bv_i = (const float*)d_in[9];
    const float* wo_i = (const float*)d_in[10]; const float* bo_i = (const float*)d_in[11];
    const float* wq_t = (const float*)d_in[12]; const float* bq_t = (const float*)d_in[13];
    const float* wk_t = (const float*)d_in[14]; const float* bk_t = (const float*)d_in[15];
    const float* wv_t = (const float*)d_in[16]; const float* bv_t = (const float*)d_in[17];
    const float* wo_t = (const float*)d_in[18]; const float* bo_t = (const float*)d_in[19];
    const float* lng_i = (const float*)d_in[20]; const float* lnb_i = (const float*)d_in[21];
    const float* lng_t = (const float*)d_in[22]; const float* lnb_t = (const float*)d_in[23];
    const float* enh_w = (const float*)d_in[24]; const float* enh_b = (const float*)d_in[25];
    const float* incw  = (const float*)d_in[26]; const float* incb  = (const float*)d_in[27];
    float* out = (float*)d_out;
    u16* wsp = (u16*)d_ws;
    u16* B0 = wsp;
    u16* B1 = wsp + 1 * (size_t)BUF_ELEMS;
    u16* B2 = wsp + 2 * (size_t)BUF_ELEMS;
    u16* B3 = wsp + 3 * (size_t)BUF_ELEMS;
    u16* B4 = wsp + 4 * (size_t)BUF_ELEMS;
    u16* B5 = wsp + 5 * (size_t)BUF_ELEMS;
    u16* wbase = wsp + 6 * (size_t)BUF_ELEMS;
    u16* WtA   = wbase;                 // [768][256]: Wq_i^T, Wk_t^T, Wv_t^T
    u16* WtB   = wbase + 196608;        // [768][256]: Wq_t^T, Wk_i^T, Wv_i^T
    u16* Wt_oi = wbase + 393216;
    u16* Wt_ot = wbase + 458752;
    u16* Wt_en = wbase + 524288;        // [256][512]
    float* biasA = (float*)(wbase + 655360);  // [768]
    float* biasB = biasA + 768;

    dim3 blk(256);
    // ---- prep: weights + biases + inconsistency/passthrough ----
    WT wt;
    wt.src[0] = wq_i; wt.dst[0] = WtA;
    wt.src[1] = wk_t; wt.dst[1] = WtA + 65536;
    wt.src[2] = wv_t; wt.dst[2] = WtA + 131072;
    wt.src[3] = wq_t; wt.dst[3] = WtB;
    wt.src[4] = wk_i; wt.dst[4] = WtB + 65536;
    wt.src[5] = wv_i; wt.dst[5] = WtB + 131072;
    wt.src[6] = wo_i; wt.dst[6] = Wt_oi;
    wt.src[7] = wo_t; wt.dst[7] = Wt_ot;
    wt.src[8] = enh_w; wt.dst[8] = Wt_en;
    wt.bs[0] = bq_i; wt.bs[1] = bk_t; wt.bs[2] = bv_t;
    wt.bs[3] = bq_t; wt.bs[4] = bk_i; wt.bs[5] = bv_i;
    wt.bA = biasA; wt.bB = biasB;
    wt.img_sp = img_sp; wt.txt_sp = txt_sp; wt.incw = incw; wt.incb = incb;
    wt.out_inc = out + 4194304; wt.out_img = out + 4198400; wt.out_txt = out + 4202496;
    wtrans_kernel<<<177, blk, 0, stream>>>(wt);

    // ---- merged QKV projections: one dispatch, img+txt M-stacked ----
    // img -> (Q_i2t=B0, K_t2i=B4, V_t2i=B5); txt -> (Q_t2i=B3, K_i2t=B1, V_i2t=B2)
    gemm_mfma<0><<<1536, blk, 0, stream>>>(img, txt, nullptr, nullptr,
                                           WtA, WtB, biasA, biasB,
                                           B0, B4, B5, B3, B1, B2);
    // ---- both attentions, output in-place over Q ----
    attn_mfma<<<2048, blk, 0, stream>>>(B0, B1, B2, B0, B3, B4, B5, B3);
    // ---- output projections, M-stacked ----
    gemm_mfma<1><<<512, blk, 0, stream>>>(nullptr, nullptr, B0, B3,
                                          Wt_oi, Wt_ot, bo_i, bo_t,
                                          B1, B4, nullptr, nullptr, nullptr, nullptr);
    // ---- residual + LN, both halves ----
    ln_res_kernel<<<8192, blk, 0, stream>>>(B1, B4, img, txt,
                                            lng_i, lnb_i, lng_t, lnb_t, B2, B5);
    // ---- enhancement (concat-K, fp32 out) ----
    gemm_mfma<2><<<256, blk, 0, stream>>>(nullptr, nullptr, B2, B5,
                                          Wt_en, nullptr, enh_b, nullptr,
                                          out, nullptr, nullptr, nullptr, nullptr, nullptr);
}